// Round 12
// baseline (365.637 us; speedup 1.0000x reference)
//
#include <hip/hip_runtime.h>
#include <hip/hip_bf16.h>
#include <math.h>

typedef __attribute__((ext_vector_type(8))) short bf16x8;
typedef __attribute__((ext_vector_type(4))) float f32x4;

__device__ inline ushort f2bf(float f) {
    uint u = __float_as_uint(f);
    uint r = u + 0x7fffu + ((u >> 16) & 1u);
    return (ushort)(r >> 16);
}
__device__ inline float bf2f(ushort h) { return __uint_as_float(((uint)h) << 16); }

// gelu tanh-approx via sigmoid identity: 0.5x(1+tanh(z)) = x/(1+exp(-2z))
__device__ inline float gelu_fast(float x) {
    float z2 = 1.5957691216057308f * (x + 0.044715f * x * x * x);  // 2*sqrt(2/pi)*(...)
    return x / (1.0f + __expf(-z2));
}

// ---------------- pass A: degree histogram + per-edge rank ----------------

__global__ void deg_rank_kernel(const int* __restrict__ col, int* __restrict__ deg,
                                int* __restrict__ rank, int E) {
    int e = blockIdx.x * blockDim.x + threadIdx.x;
    if (e < E) rank[e] = atomicAdd(&deg[col[e]], 1);
}

__global__ void dinv_kernel(const int* __restrict__ deg, float* __restrict__ dinv, int M) {
    int i = blockIdx.x * blockDim.x + threadIdx.x;
    if (i < M) dinv[i] = rsqrtf((float)deg[i] + 1.0f);   // +1 self loop
}

// ---------------- hierarchical exclusive scan of deg -> off ----------------

__global__ void block_reduce_kernel(const int* __restrict__ deg, int* __restrict__ bsum, int M) {
    __shared__ int s[256];
    int i = blockIdx.x * 256 + threadIdx.x;
    s[threadIdx.x] = (i < M) ? deg[i] : 0;
    __syncthreads();
    for (int o = 128; o > 0; o >>= 1) {
        if (threadIdx.x < o) s[threadIdx.x] += s[threadIdx.x + o];
        __syncthreads();
    }
    if (threadIdx.x == 0) bsum[blockIdx.x] = s[0];
}

__global__ void scan_bsum_kernel(int* __restrict__ bsum, int nb) {
    __shared__ int s[512];
    int t = threadIdx.x;
    int orig = (t < nb) ? bsum[t] : 0;
    s[t] = orig;
    __syncthreads();
    for (int o = 1; o < 512; o <<= 1) {
        int v = 0;
        if (t >= o) v = s[t - o];
        __syncthreads();
        if (t >= o) s[t] += v;
        __syncthreads();
    }
    if (t < nb) bsum[t] = s[t] - orig;  // exclusive
}

__global__ void scan_offsets_kernel(const int* __restrict__ deg, const int* __restrict__ bsum,
                                    int* __restrict__ off, int M) {
    __shared__ int s[256];
    int i = blockIdx.x * 256 + threadIdx.x;
    int orig = (i < M) ? deg[i] : 0;
    s[threadIdx.x] = orig;
    __syncthreads();
    for (int o = 1; o < 256; o <<= 1) {
        int v = 0;
        if (threadIdx.x >= o) v = s[threadIdx.x - o];
        __syncthreads();
        if (threadIdx.x >= o) s[threadIdx.x] += v;
        __syncthreads();
    }
    if (i < M) off[i] = bsum[blockIdx.x] + s[threadIdx.x] - orig;  // exclusive
}

// ---------------- pass B: atomic-free CSR scatter ----------------

__global__ void fill_sorted_kernel(const int* __restrict__ row, const int* __restrict__ col,
                                   const int* __restrict__ off, const int* __restrict__ rank,
                                   int* __restrict__ rs, int E) {
    int e = blockIdx.x * blockDim.x + threadIdx.x;
    if (e < E) rs[off[col[e]] + rank[e]] = row[e];
}

// ---------------- weight prep: transpose + bf16 hi/lo split ----------------

__global__ void prep_weights(const float* __restrict__ W1, const float* __restrict__ W2,
                             ushort* __restrict__ wt1h, ushort* __restrict__ wt1l,
                             ushort* __restrict__ wt2h, ushort* __restrict__ wt2l) {
    int idx = blockIdx.x * 256 + threadIdx.x;
    if (idx < 128 * 256) {
        int k = idx >> 8, n = idx & 255;
        float f = W1[idx];
        ushort h = f2bf(f);
        wt1h[n * 128 + k] = h;
        wt1l[n * 128 + k] = f2bf(f - bf2f(h));
    } else if (idx < 2 * 128 * 256) {
        int i2 = idx - 128 * 256;
        int k = i2 >> 7, n = i2 & 127;
        float f = W2[i2];
        ushort h = f2bf(f);
        wt2h[n * 256 + k] = h;
        wt2l[n * 256 + k] = f2bf(f - bf2f(h));
    }
}

// ---------------- x -> bf16 table scaled by dinv[node] (8 elems/thread) ----------------

__global__ void to_bf16_scaled_kernel(const float* __restrict__ in, const float* __restrict__ dinv,
                                      ushort* __restrict__ out, int n8) {
    int i = blockIdx.x * 256 + threadIdx.x;
    if (i >= n8) return;
    float s = dinv[i >> 4];               // 16 chunks of 8 per 128-wide row
    float4 a = *(const float4*)(in + (size_t)i * 8);
    float4 b = *(const float4*)(in + (size_t)i * 8 + 4);
    ushort4 u0 = make_ushort4(f2bf(a.x * s), f2bf(a.y * s), f2bf(a.z * s), f2bf(a.w * s));
    ushort4 u1 = make_ushort4(f2bf(b.x * s), f2bf(b.y * s), f2bf(b.z * s), f2bf(b.w * s));
    *(ushort4*)(out + (size_t)i * 8) = u0;
    *(ushort4*)(out + (size_t)i * 8 + 4) = u1;
}

// ---------------- fused MLP, operand-swapped MFMA ----------------
// Computes h^T = mfma(W1frag, aggxfrag): C layout -> node = lane&15,
// outcol = lk*4+reg (4 CONSECUTIVE cols per lane) => packed 8B stores.
// Then out^T = mfma(W2frag, hfrag), packed 8B global stores, dinv-scaled.
// 32 rows/block (M % 32 == 0: no bounds checks), 4 waves.

__global__ __launch_bounds__(256) void gemm_fused(const ushort* __restrict__ A,
                                                  const ushort* __restrict__ wt1h,
                                                  const ushort* __restrict__ wt1l,
                                                  const float* __restrict__ b1,
                                                  const ushort* __restrict__ wt2h,
                                                  const ushort* __restrict__ wt2l,
                                                  const float* __restrict__ dinv,
                                                  ushort* __restrict__ Cb, int M) {
    __shared__ ushort la[32 * 128];   // aggx tile (row-XOR swizzled)
    __shared__ ushort lh[32 * 256];   // h tile (row-XOR swizzled)

    const int t = threadIdx.x;
    const int R0 = blockIdx.x * 32;

    // stage A tile (32x128 bf16)
    #pragma unroll
    for (int base = 0; base < 512; base += 256) {
        int idx = base + t;
        int r = idx >> 4;
        int c8 = idx & 15;
        bf16x8 v = *(const bf16x8*)(A + (size_t)(R0 + r) * 128 + c8 * 8);
        int byte = (r * 128 + c8 * 8) * 2;
        byte ^= (r & 7) << 4;
        *(bf16x8*)((char*)la + byte) = v;
    }
    __syncthreads();

    const int w = t >> 6, l = t & 63;
    const int lrow = l & 15;
    const int lk = l >> 4;

    // ---- gemm1 (swapped): wave w covers outcols w*64..+63, K=128 ----
    {
        const int c0 = w * 64;
        f32x4 acc[4][2] = {};      // [outcol-tile][node-tile]
        #pragma unroll
        for (int ks = 0; ks < 4; ++ks) {
            const int kb = ks * 32 + lk * 8;
            bf16x8 xf[2], wh[4], wl[4];
            #pragma unroll
            for (int m = 0; m < 2; ++m) {
                int nd = m * 16 + lrow;
                int byte = (nd * 128 + kb) * 2;
                byte ^= (nd & 7) << 4;
                xf[m] = *(const bf16x8*)((const char*)la + byte);
            }
            #pragma unroll
            for (int n = 0; n < 4; ++n) {
                int oc = c0 + n * 16 + lrow;
                wh[n] = *(const bf16x8*)&wt1h[(size_t)oc * 128 + kb];
                wl[n] = *(const bf16x8*)&wt1l[(size_t)oc * 128 + kb];
            }
            #pragma unroll
            for (int n = 0; n < 4; ++n)
                #pragma unroll
                for (int m = 0; m < 2; ++m) {
                    acc[n][m] = __builtin_amdgcn_mfma_f32_16x16x32_bf16(wh[n], xf[m], acc[n][m], 0, 0, 0);
                    acc[n][m] = __builtin_amdgcn_mfma_f32_16x16x32_bf16(wl[n], xf[m], acc[n][m], 0, 0, 0);
                }
        }
        // epilogue1: gelu(v+b1) -> packed 8B LDS stores
        #pragma unroll
        for (int n = 0; n < 4; ++n) {
            int ob = c0 + n * 16 + lk * 4;       // 4 consecutive outcols
            float4 bb = *(const float4*)(b1 + ob);
            #pragma unroll
            for (int m = 0; m < 2; ++m) {
                int nd = m * 16 + lrow;
                ushort4 pk;
                pk.x = f2bf(gelu_fast(acc[n][m][0] + bb.x));
                pk.y = f2bf(gelu_fast(acc[n][m][1] + bb.y));
                pk.z = f2bf(gelu_fast(acc[n][m][2] + bb.z));
                pk.w = f2bf(gelu_fast(acc[n][m][3] + bb.w));
                int byte = (nd * 256 + ob) * 2;
                byte ^= (nd & 7) << 4;
                *(ushort4*)((char*)lh + byte) = pk;
            }
        }
    }
    __syncthreads();

    // ---- gemm2 (swapped): wave w covers outcols2 w*32..+31, K=256 ----
    {
        const int c0 = w * 32;
        f32x4 acc2[2][2] = {};
        #pragma unroll
        for (int ks = 0; ks < 8; ++ks) {
            const int kb = ks * 32 + lk * 8;
            bf16x8 hf[2], wh[2], wl[2];
            #pragma unroll
            for (int m = 0; m < 2; ++m) {
                int nd = m * 16 + lrow;
                int byte = (nd * 256 + kb) * 2;
                byte ^= (nd & 7) << 4;
                hf[m] = *(const bf16x8*)((const char*)lh + byte);
            }
            #pragma unroll
            for (int n = 0; n < 2; ++n) {
                int oc = c0 + n * 16 + lrow;
                wh[n] = *(const bf16x8*)&wt2h[(size_t)oc * 256 + kb];
                wl[n] = *(const bf16x8*)&wt2l[(size_t)oc * 256 + kb];
            }
            #pragma unroll
            for (int n = 0; n < 2; ++n)
                #pragma unroll
                for (int m = 0; m < 2; ++m) {
                    acc2[n][m] = __builtin_amdgcn_mfma_f32_16x16x32_bf16(wh[n], hf[m], acc2[n][m], 0, 0, 0);
                    acc2[n][m] = __builtin_amdgcn_mfma_f32_16x16x32_bf16(wl[n], hf[m], acc2[n][m], 0, 0, 0);
                }
        }
        // epilogue2: dinv-scaled bf16, packed 8B global stores (in place)
        #pragma unroll
        for (int m = 0; m < 2; ++m) {
            int nd = m * 16 + lrow;
            float sc = dinv[R0 + nd];
            #pragma unroll
            for (int n = 0; n < 2; ++n) {
                int ob = c0 + n * 16 + lk * 4;
                ushort4 pk;
                pk.x = f2bf(acc2[n][m][0] * sc);
                pk.y = f2bf(acc2[n][m][1] * sc);
                pk.z = f2bf(acc2[n][m][2] * sc);
                pk.w = f2bf(acc2[n][m][3] * sc);
                *(ushort4*)(Cb + (size_t)(R0 + nd) * 128 + ob) = pk;
            }
        }
    }
}

// ---------------- segment-sum gather over pre-scaled bf16 table, F=128 ----------------

template <bool BIAS, bool OUTBF>
__global__ __launch_bounds__(256) void gather_sum_kernel(const int* __restrict__ off,
                                                         const int* __restrict__ deg,
                                                         const int* __restrict__ rs,
                                                         const float* __restrict__ dinv,
                                                         const ushort* __restrict__ srcb,
                                                         const float* __restrict__ b,
                                                         float* __restrict__ dstf,
                                                         ushort* __restrict__ dstb, int M) {
    int wid = (blockIdx.x * 256 + threadIdx.x) >> 6;
    int lane = threadIdx.x & 63;
    int grp = lane >> 4;      // 0..3: which edge of the quad
    int l16 = lane & 15;      // feature block: 8 bf16 = 16B
    if (wid >= M) return;
    int s0 = off[wid];
    int n = deg[wid];
    float acc[8] = {};

    // self row (group 0 only, counts once)
    if (grp == 0) {
        bf16x8 u = *(const bf16x8*)(srcb + (size_t)wid * 128 + l16 * 8);
        #pragma unroll
        for (int i = 0; i < 8; ++i) acc[i] += bf2f((ushort)u[i]);
    }

    int j = 0;
    for (; j + 4 <= n; j += 4) {
        int r = rs[s0 + j + grp];
        bf16x8 u = *(const bf16x8*)(srcb + (size_t)r * 128 + l16 * 8);
        #pragma unroll
        for (int i = 0; i < 8; ++i) acc[i] += bf2f((ushort)u[i]);
    }
    if (j + grp < n) {
        int r = rs[s0 + j + grp];
        bf16x8 u = *(const bf16x8*)(srcb + (size_t)r * 128 + l16 * 8);
        #pragma unroll
        for (int i = 0; i < 8; ++i) acc[i] += bf2f((ushort)u[i]);
    }

    #pragma unroll
    for (int i = 0; i < 8; ++i) {
        acc[i] += __shfl_xor(acc[i], 16);
        acc[i] += __shfl_xor(acc[i], 32);
    }

    if (grp == 0) {
        float sc = dinv[wid];
        #pragma unroll
        for (int i = 0; i < 8; ++i) acc[i] *= sc;
        if constexpr (BIAS) {
            float4 b0 = *(const float4*)(b + l16 * 8);
            float4 b1v = *(const float4*)(b + l16 * 8 + 4);
            acc[0] += b0.x; acc[1] += b0.y; acc[2] += b0.z; acc[3] += b0.w;
            acc[4] += b1v.x; acc[5] += b1v.y; acc[6] += b1v.z; acc[7] += b1v.w;
        }
        if constexpr (OUTBF) {
            bf16x8 o;
            #pragma unroll
            for (int i = 0; i < 8; ++i) o[i] = (short)f2bf(acc[i]);
            *(bf16x8*)(dstb + (size_t)wid * 128 + l16 * 8) = o;
        } else {
            float4 o0 = make_float4(acc[0], acc[1], acc[2], acc[3]);
            float4 o1 = make_float4(acc[4], acc[5], acc[6], acc[7]);
            *(float4*)(dstf + (size_t)wid * 128 + l16 * 8) = o0;
            *(float4*)(dstf + (size_t)wid * 128 + l16 * 8 + 4) = o1;
        }
    }
}

// ---------------- launch ----------------

extern "C" void kernel_launch(void* const* d_in, const int* in_sizes, int n_in,
                              void* d_out, int out_size, void* d_ws, size_t ws_size,
                              hipStream_t stream) {
    const float* x  = (const float*)d_in[0];
    const int*   ei = (const int*)d_in[1];
    const float* W1 = (const float*)d_in[2];
    const float* b1 = (const float*)d_in[3];
    const float* W2 = (const float*)d_in[4];
    const float* b2 = (const float*)d_in[5];

    const int M = in_sizes[0] / 128;      // 100000 (M % 32 == 0)
    const int E = in_sizes[1] / 2;        // 1600000
    const int* row = ei;
    const int* col = ei + E;

    // High-water ~66 MB.
    ushort* xb    = (ushort*)d_ws;              // 12,800,000 us (x*dinv, bf16)
    ushort* aggxb = xb + 12800000;              // 12,800,000 us [N,128]
    ushort* xw2b  = aggxb;                      // IN-PLACE alias (fused gemm same-row)
    float*  dinv  = (float*)(aggxb + 12800000); // 102,400 f
    int*    deg   = (int*)(dinv + 102400);      // 102,400 i  (memset full padded span!)
    int*    off   = deg + 102400;               // 102,400 i
    int*    rank  = off + 102400;               // 1,600,000 i
    int*    rs    = rank + 1600000;             // 1,600,000 i
    int*    bsum  = rs + 1600000;               // 1,024 i
    ushort* wt1h  = (ushort*)(bsum + 1024);     // 32,768 us each
    ushort* wt1l  = wt1h + 32768;
    ushort* wt2h  = wt1l + 32768;
    ushort* wt2l  = wt2h + 32768;
    float*  outw  = (float*)d_out;

    const int nb = (M + 255) / 256;

    hipMemsetAsync(deg, 0, (size_t)102400 * sizeof(int), stream);  // full padded span

    deg_rank_kernel<<<(E + 255) / 256, 256, 0, stream>>>(col, deg, rank, E);
    dinv_kernel<<<(M + 255) / 256, 256, 0, stream>>>(deg, dinv, M);

    block_reduce_kernel<<<nb, 256, 0, stream>>>(deg, bsum, M);
    scan_bsum_kernel<<<1, 512, 0, stream>>>(bsum, nb);
    scan_offsets_kernel<<<nb, 256, 0, stream>>>(deg, bsum, off, M);

    fill_sorted_kernel<<<(E + 255) / 256, 256, 0, stream>>>(row, col, off, rank, rs, E);

    prep_weights<<<256, 256, 0, stream>>>(W1, W2, wt1h, wt1l, wt2h, wt2l);
    to_bf16_scaled_kernel<<<(M * 16 + 255) / 256, 256, 0, stream>>>(x, dinv, xb, M * 16);

    // layer 1 aggregate (self from table), bf16 out
    gather_sum_kernel<false, true><<<(M * 64 + 255) / 256, 256, 0, stream>>>(
        off, deg, rs, dinv, xb, nullptr, nullptr, aggxb, M);

    // fused MLP: aggxb -> (gemm1+gelu+gemm2) -> dinv-scaled bf16 xw2b (in place)
    gemm_fused<<<M / 32, 256, 0, stream>>>(aggxb, wt1h, wt1l, b1,
                                           wt2h, wt2l, dinv, xw2b, M);

    // layer 2 aggregate (self from table) + bias, fp32 out
    gather_sum_kernel<true, false><<<(M * 64 + 255) / 256, 256, 0, stream>>>(
        off, deg, rs, dinv, xw2b, b2, outw, nullptr, M);
}

// Round 13
// 335.014 us; speedup vs baseline: 1.0914x; 1.0914x over previous
//
#include <hip/hip_runtime.h>
#include <hip/hip_bf16.h>
#include <math.h>

typedef __attribute__((ext_vector_type(8))) short bf16x8;
typedef __attribute__((ext_vector_type(4))) float f32x4;

__device__ inline ushort f2bf(float f) {
    uint u = __float_as_uint(f);
    uint r = u + 0x7fffu + ((u >> 16) & 1u);
    return (ushort)(r >> 16);
}
__device__ inline float bf2f(ushort h) { return __uint_as_float(((uint)h) << 16); }

// gelu tanh-approx via sigmoid identity: 0.5x(1+tanh(z)) = x/(1+exp(-2z))
__device__ inline float gelu_fast(float x) {
    float z2 = 1.5957691216057308f * (x + 0.044715f * x * x * x);
    return x / (1.0f + __expf(-z2));
}

// ---------------- pass A: degree histogram + per-edge rank ----------------

__global__ void deg_rank_kernel(const int* __restrict__ col, int* __restrict__ deg,
                                int* __restrict__ rank, int E) {
    int e = blockIdx.x * blockDim.x + threadIdx.x;
    if (e < E) rank[e] = atomicAdd(&deg[col[e]], 1);
}

__global__ void dinv_kernel(const int* __restrict__ deg, float* __restrict__ dinv, int M) {
    int i = blockIdx.x * blockDim.x + threadIdx.x;
    if (i < M) dinv[i] = rsqrtf((float)deg[i] + 1.0f);   // +1 self loop
}

// ---------------- hierarchical exclusive scan of deg -> off ----------------

__global__ void block_reduce_kernel(const int* __restrict__ deg, int* __restrict__ bsum, int M) {
    __shared__ int s[256];
    int i = blockIdx.x * 256 + threadIdx.x;
    s[threadIdx.x] = (i < M) ? deg[i] : 0;
    __syncthreads();
    for (int o = 128; o > 0; o >>= 1) {
        if (threadIdx.x < o) s[threadIdx.x] += s[threadIdx.x + o];
        __syncthreads();
    }
    if (threadIdx.x == 0) bsum[blockIdx.x] = s[0];
}

__global__ void scan_bsum_kernel(int* __restrict__ bsum, int nb) {
    __shared__ int s[512];
    int t = threadIdx.x;
    int orig = (t < nb) ? bsum[t] : 0;
    s[t] = orig;
    __syncthreads();
    for (int o = 1; o < 512; o <<= 1) {
        int v = 0;
        if (t >= o) v = s[t - o];
        __syncthreads();
        if (t >= o) s[t] += v;
        __syncthreads();
    }
    if (t < nb) bsum[t] = s[t] - orig;  // exclusive
}

__global__ void scan_offsets_kernel(const int* __restrict__ deg, const int* __restrict__ bsum,
                                    int* __restrict__ off, int M) {
    __shared__ int s[256];
    int i = blockIdx.x * 256 + threadIdx.x;
    int orig = (i < M) ? deg[i] : 0;
    s[threadIdx.x] = orig;
    __syncthreads();
    for (int o = 1; o < 256; o <<= 1) {
        int v = 0;
        if (threadIdx.x >= o) v = s[threadIdx.x - o];
        __syncthreads();
        if (threadIdx.x >= o) s[threadIdx.x] += v;
        __syncthreads();
    }
    if (i < M) off[i] = bsum[blockIdx.x] + s[threadIdx.x] - orig;  // exclusive
}

// ---------------- pass B: atomic-free CSR scatter ----------------

__global__ void fill_sorted_kernel(const int* __restrict__ row, const int* __restrict__ col,
                                   const int* __restrict__ off, const int* __restrict__ rank,
                                   int* __restrict__ rs, int E) {
    int e = blockIdx.x * blockDim.x + threadIdx.x;
    if (e < E) rs[off[col[e]] + rank[e]] = row[e];
}

// ---------------- weight prep: transpose + bf16 hi/lo split ----------------

__global__ void prep_weights(const float* __restrict__ W1, const float* __restrict__ W2,
                             ushort* __restrict__ wt1h, ushort* __restrict__ wt1l,
                             ushort* __restrict__ wt2h, ushort* __restrict__ wt2l) {
    int idx = blockIdx.x * 256 + threadIdx.x;
    if (idx < 128 * 256) {
        int k = idx >> 8, n = idx & 255;
        float f = W1[idx];
        ushort h = f2bf(f);
        wt1h[n * 128 + k] = h;
        wt1l[n * 128 + k] = f2bf(f - bf2f(h));
    } else if (idx < 2 * 128 * 256) {
        int i2 = idx - 128 * 256;
        int k = i2 >> 7, n = i2 & 127;
        float f = W2[i2];
        ushort h = f2bf(f);
        wt2h[n * 256 + k] = h;
        wt2l[n * 256 + k] = f2bf(f - bf2f(h));
    }
}

// ---------------- x -> bf16 table scaled by dinv[node] (8 elems/thread) ----------------

__global__ void to_bf16_scaled_kernel(const float* __restrict__ in, const float* __restrict__ dinv,
                                      ushort* __restrict__ out, int n8) {
    int i = blockIdx.x * 256 + threadIdx.x;
    if (i >= n8) return;
    float s = dinv[i >> 4];
    float4 a = *(const float4*)(in + (size_t)i * 8);
    float4 b = *(const float4*)(in + (size_t)i * 8 + 4);
    ushort4 u0 = make_ushort4(f2bf(a.x * s), f2bf(a.y * s), f2bf(a.z * s), f2bf(a.w * s));
    ushort4 u1 = make_ushort4(f2bf(b.x * s), f2bf(b.y * s), f2bf(b.z * s), f2bf(b.w * s));
    *(ushort4*)(out + (size_t)i * 8) = u0;
    *(ushort4*)(out + (size_t)i * 8 + 4) = u1;
}

// ---------------- fused MLP v2: 64 rows/block, hoisted weight registers ----------------
// Swapped-operand MFMA (C: node = lane&15, outcol = lk*4+reg).
// All weight fragments for a GEMM are loaded into registers BEFORE its MFMA
// loop (32 back-to-back 16B loads pipeline their L2 latency); inner loop
// touches only LDS + MFMA.

__global__ __launch_bounds__(256) void gemm_fused(const ushort* __restrict__ A,
                                                  const ushort* __restrict__ wt1h,
                                                  const ushort* __restrict__ wt1l,
                                                  const float* __restrict__ b1,
                                                  const ushort* __restrict__ wt2h,
                                                  const ushort* __restrict__ wt2l,
                                                  const float* __restrict__ dinv,
                                                  ushort* __restrict__ Cb, int M) {
    __shared__ ushort la[64 * 128];   // aggx tile (row-XOR swizzled)  16KB
    __shared__ ushort lh[64 * 256];   // h tile (row-XOR swizzled)     32KB

    const int t = threadIdx.x;
    const int R0 = blockIdx.x * 64;

    // stage A tile (64x128 bf16), 4 chunks/thread
    #pragma unroll
    for (int base = 0; base < 1024; base += 256) {
        int idx = base + t;
        int r = idx >> 4;
        int c8 = idx & 15;
        int gr = R0 + r;
        bf16x8 v = {};
        if (gr < M) v = *(const bf16x8*)(A + (size_t)gr * 128 + c8 * 8);
        int byte = (r * 128 + c8 * 8) * 2;
        byte ^= (r & 7) << 4;
        *(bf16x8*)((char*)la + byte) = v;
    }

    const int w = t >> 6, l = t & 63;
    const int lrow = l & 15;
    const int lk = l >> 4;

    // ---- hoist W1 fragments (wave w: outcols w*64..+63, K=128) ----
    bf16x8 w1h[4][4], w1l[4][4];      // [n][ks] -> 128 VGPR
    {
        const int c0 = w * 64;
        #pragma unroll
        for (int n = 0; n < 4; ++n) {
            int oc = c0 + n * 16 + lrow;
            #pragma unroll
            for (int ks = 0; ks < 4; ++ks) {
                int kb = ks * 32 + lk * 8;
                w1h[n][ks] = *(const bf16x8*)&wt1h[(size_t)oc * 128 + kb];
                w1l[n][ks] = *(const bf16x8*)&wt1l[(size_t)oc * 128 + kb];
            }
        }
    }
    __syncthreads();

    // ---- gemm1: pure LDS + MFMA ----
    {
        const int c0 = w * 64;
        f32x4 acc[4][4] = {};          // [n outcol-tile][m node-tile]
        #pragma unroll
        for (int ks = 0; ks < 4; ++ks) {
            const int kb = ks * 32 + lk * 8;
            bf16x8 xf[4];
            #pragma unroll
            for (int m = 0; m < 4; ++m) {
                int nd = m * 16 + lrow;
                int byte = (nd * 128 + kb) * 2;
                byte ^= (nd & 7) << 4;
                xf[m] = *(const bf16x8*)((const char*)la + byte);
            }
            #pragma unroll
            for (int n = 0; n < 4; ++n)
                #pragma unroll
                for (int m = 0; m < 4; ++m) {
                    acc[n][m] = __builtin_amdgcn_mfma_f32_16x16x32_bf16(w1h[n][ks], xf[m], acc[n][m], 0, 0, 0);
                    acc[n][m] = __builtin_amdgcn_mfma_f32_16x16x32_bf16(w1l[n][ks], xf[m], acc[n][m], 0, 0, 0);
                }
        }
        // epilogue1: gelu(v+b1) -> packed 8B LDS stores
        #pragma unroll
        for (int n = 0; n < 4; ++n) {
            int ob = c0 + n * 16 + lk * 4;
            float4 bb = *(const float4*)(b1 + ob);
            #pragma unroll
            for (int m = 0; m < 4; ++m) {
                int nd = m * 16 + lrow;
                ushort4 pk;
                pk.x = f2bf(gelu_fast(acc[n][m][0] + bb.x));
                pk.y = f2bf(gelu_fast(acc[n][m][1] + bb.y));
                pk.z = f2bf(gelu_fast(acc[n][m][2] + bb.z));
                pk.w = f2bf(gelu_fast(acc[n][m][3] + bb.w));
                int byte = (nd * 256 + ob) * 2;
                byte ^= (nd & 7) << 4;
                *(ushort4*)((char*)lh + byte) = pk;
            }
        }
    }

    // ---- hoist W2 fragments (wave w: outcols2 w*32..+31, K=256) ----
    bf16x8 w2h[2][8], w2l[2][8];      // [n][ks] -> 128 VGPR (W1 regs dead now)
    {
        const int c0 = w * 32;
        #pragma unroll
        for (int n = 0; n < 2; ++n) {
            int oc = c0 + n * 16 + lrow;
            #pragma unroll
            for (int ks = 0; ks < 8; ++ks) {
                int kb = ks * 32 + lk * 8;
                w2h[n][ks] = *(const bf16x8*)&wt2h[(size_t)oc * 256 + kb];
                w2l[n][ks] = *(const bf16x8*)&wt2l[(size_t)oc * 256 + kb];
            }
        }
    }
    __syncthreads();

    // ---- gemm2: pure LDS + MFMA ----
    {
        const int c0 = w * 32;
        f32x4 acc2[2][4] = {};
        #pragma unroll
        for (int ks = 0; ks < 8; ++ks) {
            const int kb = ks * 32 + lk * 8;
            bf16x8 hf[4];
            #pragma unroll
            for (int m = 0; m < 4; ++m) {
                int nd = m * 16 + lrow;
                int byte = (nd * 256 + kb) * 2;
                byte ^= (nd & 7) << 4;
                hf[m] = *(const bf16x8*)((const char*)lh + byte);
            }
            #pragma unroll
            for (int n = 0; n < 2; ++n)
                #pragma unroll
                for (int m = 0; m < 4; ++m) {
                    acc2[n][m] = __builtin_amdgcn_mfma_f32_16x16x32_bf16(w2h[n][ks], hf[m], acc2[n][m], 0, 0, 0);
                    acc2[n][m] = __builtin_amdgcn_mfma_f32_16x16x32_bf16(w2l[n][ks], hf[m], acc2[n][m], 0, 0, 0);
                }
        }
        // epilogue2: dinv-scaled bf16, packed 8B global stores (in place)
        #pragma unroll
        for (int m = 0; m < 4; ++m) {
            int nd = m * 16 + lrow;
            int grow = R0 + nd;
            if (grow < M) {
                float sc = dinv[grow];
                #pragma unroll
                for (int n = 0; n < 2; ++n) {
                    int ob = c0 + n * 16 + lk * 4;
                    ushort4 pk;
                    pk.x = f2bf(acc2[n][m][0] * sc);
                    pk.y = f2bf(acc2[n][m][1] * sc);
                    pk.z = f2bf(acc2[n][m][2] * sc);
                    pk.w = f2bf(acc2[n][m][3] * sc);
                    *(ushort4*)(Cb + (size_t)grow * 128 + ob) = pk;
                }
            }
        }
    }
}

// ---------------- segment-sum gather over pre-scaled bf16 table, F=128 ----------------

template <bool BIAS, bool OUTBF>
__global__ __launch_bounds__(256) void gather_sum_kernel(const int* __restrict__ off,
                                                         const int* __restrict__ deg,
                                                         const int* __restrict__ rs,
                                                         const float* __restrict__ dinv,
                                                         const ushort* __restrict__ srcb,
                                                         const float* __restrict__ b,
                                                         float* __restrict__ dstf,
                                                         ushort* __restrict__ dstb, int M) {
    int wid = (blockIdx.x * 256 + threadIdx.x) >> 6;
    int lane = threadIdx.x & 63;
    int grp = lane >> 4;
    int l16 = lane & 15;
    if (wid >= M) return;
    int s0 = off[wid];
    int n = deg[wid];
    float acc[8] = {};

    if (grp == 0) {
        bf16x8 u = *(const bf16x8*)(srcb + (size_t)wid * 128 + l16 * 8);
        #pragma unroll
        for (int i = 0; i < 8; ++i) acc[i] += bf2f((ushort)u[i]);
    }

    int j = 0;
    for (; j + 4 <= n; j += 4) {
        int r = rs[s0 + j + grp];
        bf16x8 u = *(const bf16x8*)(srcb + (size_t)r * 128 + l16 * 8);
        #pragma unroll
        for (int i = 0; i < 8; ++i) acc[i] += bf2f((ushort)u[i]);
    }
    if (j + grp < n) {
        int r = rs[s0 + j + grp];
        bf16x8 u = *(const bf16x8*)(srcb + (size_t)r * 128 + l16 * 8);
        #pragma unroll
        for (int i = 0; i < 8; ++i) acc[i] += bf2f((ushort)u[i]);
    }

    #pragma unroll
    for (int i = 0; i < 8; ++i) {
        acc[i] += __shfl_xor(acc[i], 16);
        acc[i] += __shfl_xor(acc[i], 32);
    }

    if (grp == 0) {
        float sc = dinv[wid];
        #pragma unroll
        for (int i = 0; i < 8; ++i) acc[i] *= sc;
        if constexpr (BIAS) {
            float4 b0 = *(const float4*)(b + l16 * 8);
            float4 b1v = *(const float4*)(b + l16 * 8 + 4);
            acc[0] += b0.x; acc[1] += b0.y; acc[2] += b0.z; acc[3] += b0.w;
            acc[4] += b1v.x; acc[5] += b1v.y; acc[6] += b1v.z; acc[7] += b1v.w;
        }
        if constexpr (OUTBF) {
            bf16x8 o;
            #pragma unroll
            for (int i = 0; i < 8; ++i) o[i] = (short)f2bf(acc[i]);
            *(bf16x8*)(dstb + (size_t)wid * 128 + l16 * 8) = o;
        } else {
            float4 o0 = make_float4(acc[0], acc[1], acc[2], acc[3]);
            float4 o1 = make_float4(acc[4], acc[5], acc[6], acc[7]);
            *(float4*)(dstf + (size_t)wid * 128 + l16 * 8) = o0;
            *(float4*)(dstf + (size_t)wid * 128 + l16 * 8 + 4) = o1;
        }
    }
}

// ---------------- launch ----------------

extern "C" void kernel_launch(void* const* d_in, const int* in_sizes, int n_in,
                              void* d_out, int out_size, void* d_ws, size_t ws_size,
                              hipStream_t stream) {
    const float* x  = (const float*)d_in[0];
    const int*   ei = (const int*)d_in[1];
    const float* W1 = (const float*)d_in[2];
    const float* b1 = (const float*)d_in[3];
    const float* W2 = (const float*)d_in[4];
    const float* b2 = (const float*)d_in[5];

    const int M = in_sizes[0] / 128;      // 100000
    const int E = in_sizes[1] / 2;        // 1600000
    const int* row = ei;
    const int* col = ei + E;

    // High-water ~66 MB.
    ushort* xb    = (ushort*)d_ws;              // 12,800,000 us (x*dinv, bf16)
    ushort* aggxb = xb + 12800000;              // 12,800,000 us [N,128]
    ushort* xw2b  = aggxb;                      // IN-PLACE alias (fused gemm same-row)
    float*  dinv  = (float*)(aggxb + 12800000); // 102,400 f
    int*    deg   = (int*)(dinv + 102400);      // 102,400 i  (memset full padded span!)
    int*    off   = deg + 102400;               // 102,400 i
    int*    rank  = off + 102400;               // 1,600,000 i
    int*    rs    = rank + 1600000;             // 1,600,000 i
    int*    bsum  = rs + 1600000;               // 1,024 i
    ushort* wt1h  = (ushort*)(bsum + 1024);     // 32,768 us each
    ushort* wt1l  = wt1h + 32768;
    ushort* wt2h  = wt1l + 32768;
    ushort* wt2l  = wt2h + 32768;
    float*  outw  = (float*)d_out;

    const int nb = (M + 255) / 256;

    hipMemsetAsync(deg, 0, (size_t)102400 * sizeof(int), stream);

    deg_rank_kernel<<<(E + 255) / 256, 256, 0, stream>>>(col, deg, rank, E);
    dinv_kernel<<<(M + 255) / 256, 256, 0, stream>>>(deg, dinv, M);

    block_reduce_kernel<<<nb, 256, 0, stream>>>(deg, bsum, M);
    scan_bsum_kernel<<<1, 512, 0, stream>>>(bsum, nb);
    scan_offsets_kernel<<<nb, 256, 0, stream>>>(deg, bsum, off, M);

    fill_sorted_kernel<<<(E + 255) / 256, 256, 0, stream>>>(row, col, off, rank, rs, E);

    prep_weights<<<256, 256, 0, stream>>>(W1, W2, wt1h, wt1l, wt2h, wt2l);
    to_bf16_scaled_kernel<<<(M * 16 + 255) / 256, 256, 0, stream>>>(x, dinv, xb, M * 16);

    // layer 1 aggregate (self from table), bf16 out
    gather_sum_kernel<false, true><<<(M * 64 + 255) / 256, 256, 0, stream>>>(
        off, deg, rs, dinv, xb, nullptr, nullptr, aggxb, M);

    // fused MLP: 64 rows/block
    gemm_fused<<<(M + 63) / 64, 256, 0, stream>>>(aggxb, wt1h, wt1l, b1,
                                                  wt2h, wt2l, dinv, xw2b, M);

    // layer 2 aggregate (self from table) + bias, fp32 out
    gather_sum_kernel<true, false><<<(M * 64 + 255) / 256, 256, 0, stream>>>(
        off, deg, rs, dinv, xw2b, b2, outw, nullptr, M);
}

// Round 14
// 326.917 us; speedup vs baseline: 1.1184x; 1.0248x over previous
//
#include <hip/hip_runtime.h>
#include <hip/hip_bf16.h>
#include <math.h>

typedef __attribute__((ext_vector_type(8))) short bf16x8;
typedef __attribute__((ext_vector_type(4))) float f32x4;

__device__ inline ushort f2bf(float f) {
    uint u = __float_as_uint(f);
    uint r = u + 0x7fffu + ((u >> 16) & 1u);
    return (ushort)(r >> 16);
}
__device__ inline float bf2f(ushort h) { return __uint_as_float(((uint)h) << 16); }

// gelu tanh-approx via sigmoid identity: 0.5x(1+tanh(z)) = x/(1+exp(-2z))
__device__ inline float gelu_fast(float x) {
    float z2 = 1.5957691216057308f * (x + 0.044715f * x * x * x);
    return x / (1.0f + __expf(-z2));
}

// ---------------- pass A: degree histogram + per-edge rank ----------------

__global__ void deg_rank_kernel(const int* __restrict__ col, int* __restrict__ deg,
                                int* __restrict__ rank, int E) {
    int e = blockIdx.x * blockDim.x + threadIdx.x;
    if (e < E) rank[e] = atomicAdd(&deg[col[e]], 1);
}

__global__ void dinv_kernel(const int* __restrict__ deg, float* __restrict__ dinv, int M) {
    int i = blockIdx.x * blockDim.x + threadIdx.x;
    if (i < M) dinv[i] = rsqrtf((float)deg[i] + 1.0f);   // +1 self loop
}

// ---------------- hierarchical exclusive scan of deg -> off ----------------

__global__ void block_reduce_kernel(const int* __restrict__ deg, int* __restrict__ bsum, int M) {
    __shared__ int s[256];
    int i = blockIdx.x * 256 + threadIdx.x;
    s[threadIdx.x] = (i < M) ? deg[i] : 0;
    __syncthreads();
    for (int o = 128; o > 0; o >>= 1) {
        if (threadIdx.x < o) s[threadIdx.x] += s[threadIdx.x + o];
        __syncthreads();
    }
    if (threadIdx.x == 0) bsum[blockIdx.x] = s[0];
}

__global__ void scan_bsum_kernel(int* __restrict__ bsum, int nb) {
    __shared__ int s[512];
    int t = threadIdx.x;
    int orig = (t < nb) ? bsum[t] : 0;
    s[t] = orig;
    __syncthreads();
    for (int o = 1; o < 512; o <<= 1) {
        int v = 0;
        if (t >= o) v = s[t - o];
        __syncthreads();
        if (t >= o) s[t] += v;
        __syncthreads();
    }
    if (t < nb) bsum[t] = s[t] - orig;  // exclusive
}

__global__ void scan_offsets_kernel(const int* __restrict__ deg, const int* __restrict__ bsum,
                                    int* __restrict__ off, int M) {
    __shared__ int s[256];
    int i = blockIdx.x * 256 + threadIdx.x;
    int orig = (i < M) ? deg[i] : 0;
    s[threadIdx.x] = orig;
    __syncthreads();
    for (int o = 1; o < 256; o <<= 1) {
        int v = 0;
        if (threadIdx.x >= o) v = s[threadIdx.x - o];
        __syncthreads();
        if (threadIdx.x >= o) s[threadIdx.x] += v;
        __syncthreads();
    }
    if (i < M) off[i] = bsum[blockIdx.x] + s[threadIdx.x] - orig;  // exclusive
}

// ---------------- pass B: atomic-free CSR scatter ----------------

__global__ void fill_sorted_kernel(const int* __restrict__ row, const int* __restrict__ col,
                                   const int* __restrict__ off, const int* __restrict__ rank,
                                   int* __restrict__ rs, int E) {
    int e = blockIdx.x * blockDim.x + threadIdx.x;
    if (e < E) rs[off[col[e]] + rank[e]] = row[e];
}

// ---------------- weight prep: transpose + bf16 hi/lo split ----------------

__global__ void prep_weights(const float* __restrict__ W1, const float* __restrict__ W2,
                             ushort* __restrict__ wt1h, ushort* __restrict__ wt1l,
                             ushort* __restrict__ wt2h, ushort* __restrict__ wt2l) {
    int idx = blockIdx.x * 256 + threadIdx.x;
    if (idx < 128 * 256) {
        int k = idx >> 8, n = idx & 255;
        float f = W1[idx];
        ushort h = f2bf(f);
        wt1h[n * 128 + k] = h;
        wt1l[n * 128 + k] = f2bf(f - bf2f(h));
    } else if (idx < 2 * 128 * 256) {
        int i2 = idx - 128 * 256;
        int k = i2 >> 7, n = i2 & 127;
        float f = W2[i2];
        ushort h = f2bf(f);
        wt2h[n * 256 + k] = h;
        wt2l[n * 256 + k] = f2bf(f - bf2f(h));
    }
}

// ---------------- x -> bf16 table scaled by dinv[node] (8 elems/thread) ----------------

__global__ void to_bf16_scaled_kernel(const float* __restrict__ in, const float* __restrict__ dinv,
                                      ushort* __restrict__ out, int n8) {
    int i = blockIdx.x * 256 + threadIdx.x;
    if (i >= n8) return;
    float s = dinv[i >> 4];
    float4 a = *(const float4*)(in + (size_t)i * 8);
    float4 b = *(const float4*)(in + (size_t)i * 8 + 4);
    ushort4 u0 = make_ushort4(f2bf(a.x * s), f2bf(a.y * s), f2bf(a.z * s), f2bf(a.w * s));
    ushort4 u1 = make_ushort4(f2bf(b.x * s), f2bf(b.y * s), f2bf(b.z * s), f2bf(b.w * s));
    *(ushort4*)(out + (size_t)i * 8) = u0;
    *(ushort4*)(out + (size_t)i * 8 + 4) = u1;
}

// ---------------- fused MLP v3: 64 rows/block, full weight hoisting, no A-stage ----------------
// launch_bounds(256,2): VGPR cap 256 so both W fragment sets stay register-resident.
// gemm1 reads A fragments directly from global (L2-warm, coalesced 16B/lane).

__global__ __launch_bounds__(256, 2) void gemm_fused(const ushort* __restrict__ A,
                                                     const ushort* __restrict__ wt1h,
                                                     const ushort* __restrict__ wt1l,
                                                     const float* __restrict__ b1,
                                                     const ushort* __restrict__ wt2h,
                                                     const ushort* __restrict__ wt2l,
                                                     const float* __restrict__ dinv,
                                                     ushort* __restrict__ Cb, int M) {
    __shared__ ushort lh[64 * 256];   // h tile (row-XOR swizzled), 32KB

    const int t = threadIdx.x;
    const int R0 = blockIdx.x * 64;
    const int w = t >> 6, l = t & 63;
    const int lrow = l & 15;
    const int lk = l >> 4;

    // ---- hoist W1 fragments (wave w: outcols w*64..+63, K=128) ----
    bf16x8 w1h[4][4], w1l[4][4];      // 128 VGPR
    {
        const int c0 = w * 64;
        #pragma unroll
        for (int n = 0; n < 4; ++n) {
            int oc = c0 + n * 16 + lrow;
            #pragma unroll
            for (int ks = 0; ks < 4; ++ks) {
                int kb = ks * 32 + lk * 8;
                w1h[n][ks] = *(const bf16x8*)&wt1h[(size_t)oc * 128 + kb];
                w1l[n][ks] = *(const bf16x8*)&wt1l[(size_t)oc * 128 + kb];
            }
        }
    }

    // ---- gemm1: direct-global A fragments + register W ----
    {
        const int c0 = w * 64;
        f32x4 acc[4][4] = {};          // [n outcol-tile][m node-tile]
        #pragma unroll
        for (int ks = 0; ks < 4; ++ks) {
            const int kb = ks * 32 + lk * 8;
            bf16x8 xf[4];
            #pragma unroll
            for (int m = 0; m < 4; ++m) {
                int gr = R0 + m * 16 + lrow;
                gr = gr < M ? gr : M - 1;          // clamp (tail block)
                xf[m] = *(const bf16x8*)(A + (size_t)gr * 128 + kb);
            }
            #pragma unroll
            for (int n = 0; n < 4; ++n)
                #pragma unroll
                for (int m = 0; m < 4; ++m) {
                    acc[n][m] = __builtin_amdgcn_mfma_f32_16x16x32_bf16(w1h[n][ks], xf[m], acc[n][m], 0, 0, 0);
                    acc[n][m] = __builtin_amdgcn_mfma_f32_16x16x32_bf16(w1l[n][ks], xf[m], acc[n][m], 0, 0, 0);
                }
        }
        // epilogue1: gelu(v+b1) -> packed 8B LDS stores
        #pragma unroll
        for (int n = 0; n < 4; ++n) {
            int ob = c0 + n * 16 + lk * 4;
            float4 bb = *(const float4*)(b1 + ob);
            #pragma unroll
            for (int m = 0; m < 4; ++m) {
                int nd = m * 16 + lrow;
                ushort4 pk;
                pk.x = f2bf(gelu_fast(acc[n][m][0] + bb.x));
                pk.y = f2bf(gelu_fast(acc[n][m][1] + bb.y));
                pk.z = f2bf(gelu_fast(acc[n][m][2] + bb.z));
                pk.w = f2bf(gelu_fast(acc[n][m][3] + bb.w));
                int byte = (nd * 256 + ob) * 2;
                byte ^= (nd & 7) << 4;
                *(ushort4*)((char*)lh + byte) = pk;
            }
        }
    }

    // ---- hoist W2 fragments (wave w: outcols2 w*32..+31, K=256) ----
    bf16x8 w2h[2][8], w2l[2][8];      // 128 VGPR (W1 regs dead now)
    {
        const int c0 = w * 32;
        #pragma unroll
        for (int n = 0; n < 2; ++n) {
            int oc = c0 + n * 16 + lrow;
            #pragma unroll
            for (int ks = 0; ks < 8; ++ks) {
                int kb = ks * 32 + lk * 8;
                w2h[n][ks] = *(const bf16x8*)&wt2h[(size_t)oc * 256 + kb];
                w2l[n][ks] = *(const bf16x8*)&wt2l[(size_t)oc * 256 + kb];
            }
        }
    }
    __syncthreads();

    // ---- gemm2: LDS h + register W ----
    {
        const int c0 = w * 32;
        f32x4 acc2[2][4] = {};
        #pragma unroll
        for (int ks = 0; ks < 8; ++ks) {
            const int kb = ks * 32 + lk * 8;
            bf16x8 hf[4];
            #pragma unroll
            for (int m = 0; m < 4; ++m) {
                int nd = m * 16 + lrow;
                int byte = (nd * 256 + kb) * 2;
                byte ^= (nd & 7) << 4;
                hf[m] = *(const bf16x8*)((const char*)lh + byte);
            }
            #pragma unroll
            for (int n = 0; n < 2; ++n)
                #pragma unroll
                for (int m = 0; m < 4; ++m) {
                    acc2[n][m] = __builtin_amdgcn_mfma_f32_16x16x32_bf16(w2h[n][ks], hf[m], acc2[n][m], 0, 0, 0);
                    acc2[n][m] = __builtin_amdgcn_mfma_f32_16x16x32_bf16(w2l[n][ks], hf[m], acc2[n][m], 0, 0, 0);
                }
        }
        // epilogue2: dinv-scaled bf16, packed 8B global stores (in place)
        #pragma unroll
        for (int m = 0; m < 4; ++m) {
            int nd = m * 16 + lrow;
            int grow = R0 + nd;
            if (grow < M) {
                float sc = dinv[grow];
                #pragma unroll
                for (int n = 0; n < 2; ++n) {
                    int ob = c0 + n * 16 + lk * 4;
                    ushort4 pk;
                    pk.x = f2bf(acc2[n][m][0] * sc);
                    pk.y = f2bf(acc2[n][m][1] * sc);
                    pk.z = f2bf(acc2[n][m][2] * sc);
                    pk.w = f2bf(acc2[n][m][3] * sc);
                    *(ushort4*)(Cb + (size_t)grow * 128 + ob) = pk;
                }
            }
        }
    }
}

// ---------------- segment-sum gather, 8 edges in flight ----------------
// One wave per node; 4 groups of 16 lanes; each group keeps 2 independent
// row fetches outstanding (dual accumulators), 8 edges/wave in flight.

template <bool BIAS, bool OUTBF>
__global__ __launch_bounds__(256) void gather_sum_kernel(const int* __restrict__ off,
                                                         const int* __restrict__ deg,
                                                         const int* __restrict__ rs,
                                                         const float* __restrict__ dinv,
                                                         const ushort* __restrict__ srcb,
                                                         const float* __restrict__ b,
                                                         float* __restrict__ dstf,
                                                         ushort* __restrict__ dstb, int M) {
    int wid = (blockIdx.x * 256 + threadIdx.x) >> 6;
    int lane = threadIdx.x & 63;
    int grp = lane >> 4;
    int l16 = lane & 15;
    if (wid >= M) return;
    int s0 = off[wid];
    int n = deg[wid];
    float acc[8] = {};
    float acc2[8] = {};

    // self row (group 0 only, counts once)
    if (grp == 0) {
        bf16x8 u = *(const bf16x8*)(srcb + (size_t)wid * 128 + l16 * 8);
        #pragma unroll
        for (int i = 0; i < 8; ++i) acc[i] += bf2f((ushort)u[i]);
    }

    int j = 0;
    for (; j + 8 <= n; j += 8) {
        int r0 = rs[s0 + j + grp];
        int r1 = rs[s0 + j + 4 + grp];
        bf16x8 u0 = *(const bf16x8*)(srcb + (size_t)r0 * 128 + l16 * 8);
        bf16x8 u1 = *(const bf16x8*)(srcb + (size_t)r1 * 128 + l16 * 8);
        #pragma unroll
        for (int i = 0; i < 8; ++i) {
            acc[i] += bf2f((ushort)u0[i]);
            acc2[i] += bf2f((ushort)u1[i]);
        }
    }
    if (j + 4 <= n) {
        int r = rs[s0 + j + grp];
        bf16x8 u = *(const bf16x8*)(srcb + (size_t)r * 128 + l16 * 8);
        #pragma unroll
        for (int i = 0; i < 8; ++i) acc[i] += bf2f((ushort)u[i]);
        j += 4;
    }
    if (j + grp < n) {
        int r = rs[s0 + j + grp];
        bf16x8 u = *(const bf16x8*)(srcb + (size_t)r * 128 + l16 * 8);
        #pragma unroll
        for (int i = 0; i < 8; ++i) acc2[i] += bf2f((ushort)u[i]);
    }

    #pragma unroll
    for (int i = 0; i < 8; ++i) {
        acc[i] += acc2[i];
        acc[i] += __shfl_xor(acc[i], 16);
        acc[i] += __shfl_xor(acc[i], 32);
    }

    if (grp == 0) {
        float sc = dinv[wid];
        #pragma unroll
        for (int i = 0; i < 8; ++i) acc[i] *= sc;
        if constexpr (BIAS) {
            float4 b0 = *(const float4*)(b + l16 * 8);
            float4 b1v = *(const float4*)(b + l16 * 8 + 4);
            acc[0] += b0.x; acc[1] += b0.y; acc[2] += b0.z; acc[3] += b0.w;
            acc[4] += b1v.x; acc[5] += b1v.y; acc[6] += b1v.z; acc[7] += b1v.w;
        }
        if constexpr (OUTBF) {
            bf16x8 o;
            #pragma unroll
            for (int i = 0; i < 8; ++i) o[i] = (short)f2bf(acc[i]);
            *(bf16x8*)(dstb + (size_t)wid * 128 + l16 * 8) = o;
        } else {
            float4 o0 = make_float4(acc[0], acc[1], acc[2], acc[3]);
            float4 o1 = make_float4(acc[4], acc[5], acc[6], acc[7]);
            *(float4*)(dstf + (size_t)wid * 128 + l16 * 8) = o0;
            *(float4*)(dstf + (size_t)wid * 128 + l16 * 8 + 4) = o1;
        }
    }
}

// ---------------- launch ----------------

extern "C" void kernel_launch(void* const* d_in, const int* in_sizes, int n_in,
                              void* d_out, int out_size, void* d_ws, size_t ws_size,
                              hipStream_t stream) {
    const float* x  = (const float*)d_in[0];
    const int*   ei = (const int*)d_in[1];
    const float* W1 = (const float*)d_in[2];
    const float* b1 = (const float*)d_in[3];
    const float* W2 = (const float*)d_in[4];
    const float* b2 = (const float*)d_in[5];

    const int M = in_sizes[0] / 128;      // 100000
    const int E = in_sizes[1] / 2;        // 1600000
    const int* row = ei;
    const int* col = ei + E;

    // High-water ~66 MB.
    ushort* xb    = (ushort*)d_ws;              // 12,800,000 us (x*dinv, bf16)
    ushort* aggxb = xb + 12800000;              // 12,800,000 us [N,128]
    ushort* xw2b  = aggxb;                      // IN-PLACE alias (fused gemm same-row)
    float*  dinv  = (float*)(aggxb + 12800000); // 102,400 f
    int*    deg   = (int*)(dinv + 102400);      // 102,400 i  (memset full padded span!)
    int*    off   = deg + 102400;               // 102,400 i
    int*    rank  = off + 102400;               // 1,600,000 i
    int*    rs    = rank + 1600000;             // 1,600,000 i
    int*    bsum  = rs + 1600000;               // 1,024 i
    ushort* wt1h  = (ushort*)(bsum + 1024);     // 32,768 us each
    ushort* wt1l  = wt1h + 32768;
    ushort* wt2h  = wt1l + 32768;
    ushort* wt2l  = wt2h + 32768;
    float*  outw  = (float*)d_out;

    const int nb = (M + 255) / 256;

    hipMemsetAsync(deg, 0, (size_t)102400 * sizeof(int), stream);

    deg_rank_kernel<<<(E + 255) / 256, 256, 0, stream>>>(col, deg, rank, E);
    dinv_kernel<<<(M + 255) / 256, 256, 0, stream>>>(deg, dinv, M);

    block_reduce_kernel<<<nb, 256, 0, stream>>>(deg, bsum, M);
    scan_bsum_kernel<<<1, 512, 0, stream>>>(bsum, nb);
    scan_offsets_kernel<<<nb, 256, 0, stream>>>(deg, bsum, off, M);

    fill_sorted_kernel<<<(E + 255) / 256, 256, 0, stream>>>(row, col, off, rank, rs, E);

    prep_weights<<<256, 256, 0, stream>>>(W1, W2, wt1h, wt1l, wt2h, wt2l);
    to_bf16_scaled_kernel<<<(M * 16 + 255) / 256, 256, 0, stream>>>(x, dinv, xb, M * 16);

    // layer 1 aggregate (self from table), bf16 out
    gather_sum_kernel<false, true><<<(M * 64 + 255) / 256, 256, 0, stream>>>(
        off, deg, rs, dinv, xb, nullptr, nullptr, aggxb, M);

    // fused MLP: 64 rows/block, full weight hoisting
    gemm_fused<<<(M + 63) / 64, 256, 0, stream>>>(aggxb, wt1h, wt1l, b1,
                                                  wt2h, wt2l, dinv, xw2b, M);

    // layer 2 aggregate (self from table) + bias, fp32 out
    gather_sum_kernel<true, false><<<(M * 64 + 255) / 256, 256, 0, stream>>>(
        off, deg, rs, dinv, xw2b, b2, outw, nullptr, M);
}

// Round 15
// 303.684 us; speedup vs baseline: 1.2040x; 1.0765x over previous
//
#include <hip/hip_runtime.h>
#include <hip/hip_bf16.h>
#include <math.h>

typedef __attribute__((ext_vector_type(8))) short bf16x8;
typedef __attribute__((ext_vector_type(4))) float f32x4;

__device__ inline ushort f2bf(float f) {
    uint u = __float_as_uint(f);
    uint r = u + 0x7fffu + ((u >> 16) & 1u);
    return (ushort)(r >> 16);
}
__device__ inline float bf2f(ushort h) { return __uint_as_float(((uint)h) << 16); }

// gelu tanh-approx via sigmoid identity: 0.5x(1+tanh(z)) = x/(1+exp(-2z))
__device__ inline float gelu_fast(float x) {
    float z2 = 1.5957691216057308f * (x + 0.044715f * x * x * x);
    return x / (1.0f + __expf(-z2));
}

// ---------------- pass A: degree histogram + per-edge rank ----------------

__global__ void deg_rank_kernel(const int* __restrict__ col, int* __restrict__ deg,
                                int* __restrict__ rank, int E) {
    int e = blockIdx.x * blockDim.x + threadIdx.x;
    if (e < E) rank[e] = atomicAdd(&deg[col[e]], 1);
}

__global__ void dinv_kernel(const int* __restrict__ deg, float* __restrict__ dinv, int M) {
    int i = blockIdx.x * blockDim.x + threadIdx.x;
    if (i < M) dinv[i] = rsqrtf((float)deg[i] + 1.0f);   // +1 self loop
}

// ---------------- hierarchical exclusive scan of deg -> off ----------------

__global__ void block_reduce_kernel(const int* __restrict__ deg, int* __restrict__ bsum, int M) {
    __shared__ int s[256];
    int i = blockIdx.x * 256 + threadIdx.x;
    s[threadIdx.x] = (i < M) ? deg[i] : 0;
    __syncthreads();
    for (int o = 128; o > 0; o >>= 1) {
        if (threadIdx.x < o) s[threadIdx.x] += s[threadIdx.x + o];
        __syncthreads();
    }
    if (threadIdx.x == 0) bsum[blockIdx.x] = s[0];
}

__global__ void scan_bsum_kernel(int* __restrict__ bsum, int nb) {
    __shared__ int s[512];
    int t = threadIdx.x;
    int orig = (t < nb) ? bsum[t] : 0;
    s[t] = orig;
    __syncthreads();
    for (int o = 1; o < 512; o <<= 1) {
        int v = 0;
        if (t >= o) v = s[t - o];
        __syncthreads();
        if (t >= o) s[t] += v;
        __syncthreads();
    }
    if (t < nb) bsum[t] = s[t] - orig;  // exclusive
}

__global__ void scan_offsets_kernel(const int* __restrict__ deg, const int* __restrict__ bsum,
                                    int* __restrict__ off, int M) {
    __shared__ int s[256];
    int i = blockIdx.x * 256 + threadIdx.x;
    int orig = (i < M) ? deg[i] : 0;
    s[threadIdx.x] = orig;
    __syncthreads();
    for (int o = 1; o < 256; o <<= 1) {
        int v = 0;
        if (threadIdx.x >= o) v = s[threadIdx.x - o];
        __syncthreads();
        if (threadIdx.x >= o) s[threadIdx.x] += v;
        __syncthreads();
    }
    if (i < M) off[i] = bsum[blockIdx.x] + s[threadIdx.x] - orig;  // exclusive
}

// ---------------- pass B: atomic-free CSR scatter ----------------

__global__ void fill_sorted_kernel(const int* __restrict__ row, const int* __restrict__ col,
                                   const int* __restrict__ off, const int* __restrict__ rank,
                                   int* __restrict__ rs, int E) {
    int e = blockIdx.x * blockDim.x + threadIdx.x;
    if (e < E) rs[off[col[e]] + rank[e]] = row[e];
}

// ---------------- weight prep: transpose + plain bf16 ----------------

__global__ void prep_weights(const float* __restrict__ W1, const float* __restrict__ W2,
                             ushort* __restrict__ wt1, ushort* __restrict__ wt2) {
    int idx = blockIdx.x * 256 + threadIdx.x;
    if (idx < 128 * 256) {
        int k = idx >> 8, n = idx & 255;
        wt1[n * 128 + k] = f2bf(W1[idx]);
    } else if (idx < 2 * 128 * 256) {
        int i2 = idx - 128 * 256;
        int k = i2 >> 7, n = i2 & 127;
        wt2[n * 256 + k] = f2bf(W2[i2]);
    }
}

// ---------------- x -> bf16 table scaled by dinv[node] (8 elems/thread) ----------------

__global__ void to_bf16_scaled_kernel(const float* __restrict__ in, const float* __restrict__ dinv,
                                      ushort* __restrict__ out, int n8) {
    int i = blockIdx.x * 256 + threadIdx.x;
    if (i >= n8) return;
    float s = dinv[i >> 4];
    float4 a = *(const float4*)(in + (size_t)i * 8);
    float4 b = *(const float4*)(in + (size_t)i * 8 + 4);
    ushort4 u0 = make_ushort4(f2bf(a.x * s), f2bf(a.y * s), f2bf(a.z * s), f2bf(a.w * s));
    ushort4 u1 = make_ushort4(f2bf(b.x * s), f2bf(b.y * s), f2bf(b.z * s), f2bf(b.w * s));
    *(ushort4*)(out + (size_t)i * 8) = u0;
    *(ushort4*)(out + (size_t)i * 8 + 4) = u1;
}

// ---------------- fused MLP v4: plain-bf16 weights (half MFMA, half fetch) ----------------
// 64 rows/block, swapped-operand MFMA (C: node = lane&15, outcol = lk*4+reg).
// gemm1 reads A fragments directly from global (L2-warm); h via 32KB LDS.

__global__ __launch_bounds__(256, 2) void gemm_fused(const ushort* __restrict__ A,
                                                     const ushort* __restrict__ wt1,
                                                     const float* __restrict__ b1,
                                                     const ushort* __restrict__ wt2,
                                                     const float* __restrict__ dinv,
                                                     ushort* __restrict__ Cb, int M) {
    __shared__ ushort lh[64 * 256];   // h tile (row-XOR swizzled), 32KB

    const int t = threadIdx.x;
    const int R0 = blockIdx.x * 64;
    const int w = t >> 6, l = t & 63;
    const int lrow = l & 15;
    const int lk = l >> 4;

    // ---- hoist W1 fragments (wave w: outcols w*64..+63, K=128) ----
    bf16x8 w1[4][4];                  // 64 VGPR
    {
        const int c0 = w * 64;
        #pragma unroll
        for (int n = 0; n < 4; ++n) {
            int oc = c0 + n * 16 + lrow;
            #pragma unroll
            for (int ks = 0; ks < 4; ++ks) {
                int kb = ks * 32 + lk * 8;
                w1[n][ks] = *(const bf16x8*)&wt1[(size_t)oc * 128 + kb];
            }
        }
    }

    // ---- gemm1: direct-global A fragments + register W ----
    {
        const int c0 = w * 64;
        f32x4 acc[4][4] = {};          // [n outcol-tile][m node-tile]
        #pragma unroll
        for (int ks = 0; ks < 4; ++ks) {
            const int kb = ks * 32 + lk * 8;
            bf16x8 xf[4];
            #pragma unroll
            for (int m = 0; m < 4; ++m) {
                int gr = R0 + m * 16 + lrow;
                gr = gr < M ? gr : M - 1;          // clamp (tail block)
                xf[m] = *(const bf16x8*)(A + (size_t)gr * 128 + kb);
            }
            #pragma unroll
            for (int n = 0; n < 4; ++n)
                #pragma unroll
                for (int m = 0; m < 4; ++m)
                    acc[n][m] = __builtin_amdgcn_mfma_f32_16x16x32_bf16(w1[n][ks], xf[m], acc[n][m], 0, 0, 0);
        }
        // epilogue1: gelu(v+b1) -> packed 8B LDS stores
        #pragma unroll
        for (int n = 0; n < 4; ++n) {
            int ob = c0 + n * 16 + lk * 4;
            float4 bb = *(const float4*)(b1 + ob);
            #pragma unroll
            for (int m = 0; m < 4; ++m) {
                int nd = m * 16 + lrow;
                ushort4 pk;
                pk.x = f2bf(gelu_fast(acc[n][m][0] + bb.x));
                pk.y = f2bf(gelu_fast(acc[n][m][1] + bb.y));
                pk.z = f2bf(gelu_fast(acc[n][m][2] + bb.z));
                pk.w = f2bf(gelu_fast(acc[n][m][3] + bb.w));
                int byte = (nd * 256 + ob) * 2;
                byte ^= (nd & 7) << 4;
                *(ushort4*)((char*)lh + byte) = pk;
            }
        }
    }

    // ---- hoist W2 fragments (wave w: outcols2 w*32..+31, K=256) ----
    bf16x8 w2[2][8];                  // 64 VGPR (W1 regs dead now)
    {
        const int c0 = w * 32;
        #pragma unroll
        for (int n = 0; n < 2; ++n) {
            int oc = c0 + n * 16 + lrow;
            #pragma unroll
            for (int ks = 0; ks < 8; ++ks) {
                int kb = ks * 32 + lk * 8;
                w2[n][ks] = *(const bf16x8*)&wt2[(size_t)oc * 256 + kb];
            }
        }
    }
    __syncthreads();

    // ---- gemm2: LDS h + register W ----
    {
        const int c0 = w * 32;
        f32x4 acc2[2][4] = {};
        #pragma unroll
        for (int ks = 0; ks < 8; ++ks) {
            const int kb = ks * 32 + lk * 8;
            bf16x8 hf[4];
            #pragma unroll
            for (int m = 0; m < 4; ++m) {
                int nd = m * 16 + lrow;
                int byte = (nd * 256 + kb) * 2;
                byte ^= (nd & 7) << 4;
                hf[m] = *(const bf16x8*)((const char*)lh + byte);
            }
            #pragma unroll
            for (int n = 0; n < 2; ++n)
                #pragma unroll
                for (int m = 0; m < 4; ++m)
                    acc2[n][m] = __builtin_amdgcn_mfma_f32_16x16x32_bf16(w2[n][ks], hf[m], acc2[n][m], 0, 0, 0);
        }
        // epilogue2: dinv-scaled bf16, packed 8B global stores (in place)
        #pragma unroll
        for (int m = 0; m < 4; ++m) {
            int nd = m * 16 + lrow;
            int grow = R0 + nd;
            if (grow < M) {
                float sc = dinv[grow];
                #pragma unroll
                for (int n = 0; n < 2; ++n) {
                    int ob = c0 + n * 16 + lk * 4;
                    ushort4 pk;
                    pk.x = f2bf(acc2[n][m][0] * sc);
                    pk.y = f2bf(acc2[n][m][1] * sc);
                    pk.z = f2bf(acc2[n][m][2] * sc);
                    pk.w = f2bf(acc2[n][m][3] * sc);
                    *(ushort4*)(Cb + (size_t)grow * 128 + ob) = pk;
                }
            }
        }
    }
}

// ---------------- segment-sum gather, 8 edges in flight ----------------

template <bool BIAS, bool OUTBF>
__global__ __launch_bounds__(256) void gather_sum_kernel(const int* __restrict__ off,
                                                         const int* __restrict__ deg,
                                                         const int* __restrict__ rs,
                                                         const float* __restrict__ dinv,
                                                         const ushort* __restrict__ srcb,
                                                         const float* __restrict__ b,
                                                         float* __restrict__ dstf,
                                                         ushort* __restrict__ dstb, int M) {
    int wid = (blockIdx.x * 256 + threadIdx.x) >> 6;
    int lane = threadIdx.x & 63;
    int grp = lane >> 4;
    int l16 = lane & 15;
    if (wid >= M) return;
    int s0 = off[wid];
    int n = deg[wid];
    float acc[8] = {};
    float acc2[8] = {};

    if (grp == 0) {
        bf16x8 u = *(const bf16x8*)(srcb + (size_t)wid * 128 + l16 * 8);
        #pragma unroll
        for (int i = 0; i < 8; ++i) acc[i] += bf2f((ushort)u[i]);
    }

    int j = 0;
    for (; j + 8 <= n; j += 8) {
        int r0 = rs[s0 + j + grp];
        int r1 = rs[s0 + j + 4 + grp];
        bf16x8 u0 = *(const bf16x8*)(srcb + (size_t)r0 * 128 + l16 * 8);
        bf16x8 u1 = *(const bf16x8*)(srcb + (size_t)r1 * 128 + l16 * 8);
        #pragma unroll
        for (int i = 0; i < 8; ++i) {
            acc[i] += bf2f((ushort)u0[i]);
            acc2[i] += bf2f((ushort)u1[i]);
        }
    }
    if (j + 4 <= n) {
        int r = rs[s0 + j + grp];
        bf16x8 u = *(const bf16x8*)(srcb + (size_t)r * 128 + l16 * 8);
        #pragma unroll
        for (int i = 0; i < 8; ++i) acc[i] += bf2f((ushort)u[i]);
        j += 4;
    }
    if (j + grp < n) {
        int r = rs[s0 + j + grp];
        bf16x8 u = *(const bf16x8*)(srcb + (size_t)r * 128 + l16 * 8);
        #pragma unroll
        for (int i = 0; i < 8; ++i) acc2[i] += bf2f((ushort)u[i]);
    }

    #pragma unroll
    for (int i = 0; i < 8; ++i) {
        acc[i] += acc2[i];
        acc[i] += __shfl_xor(acc[i], 16);
        acc[i] += __shfl_xor(acc[i], 32);
    }

    if (grp == 0) {
        float sc = dinv[wid];
        #pragma unroll
        for (int i = 0; i < 8; ++i) acc[i] *= sc;
        if constexpr (BIAS) {
            float4 b0 = *(const float4*)(b + l16 * 8);
            float4 b1v = *(const float4*)(b + l16 * 8 + 4);
            acc[0] += b0.x; acc[1] += b0.y; acc[2] += b0.z; acc[3] += b0.w;
            acc[4] += b1v.x; acc[5] += b1v.y; acc[6] += b1v.z; acc[7] += b1v.w;
        }
        if constexpr (OUTBF) {
            bf16x8 o;
            #pragma unroll
            for (int i = 0; i < 8; ++i) o[i] = (short)f2bf(acc[i]);
            *(bf16x8*)(dstb + (size_t)wid * 128 + l16 * 8) = o;
        } else {
            float4 o0 = make_float4(acc[0], acc[1], acc[2], acc[3]);
            float4 o1 = make_float4(acc[4], acc[5], acc[6], acc[7]);
            *(float4*)(dstf + (size_t)wid * 128 + l16 * 8) = o0;
            *(float4*)(dstf + (size_t)wid * 128 + l16 * 8 + 4) = o1;
        }
    }
}

// ---------------- launch ----------------

extern "C" void kernel_launch(void* const* d_in, const int* in_sizes, int n_in,
                              void* d_out, int out_size, void* d_ws, size_t ws_size,
                              hipStream_t stream) {
    const float* x  = (const float*)d_in[0];
    const int*   ei = (const int*)d_in[1];
    const float* W1 = (const float*)d_in[2];
    const float* b1 = (const float*)d_in[3];
    const float* W2 = (const float*)d_in[4];
    const float* b2 = (const float*)d_in[5];

    const int M = in_sizes[0] / 128;      // 100000
    const int E = in_sizes[1] / 2;        // 1600000
    const int* row = ei;
    const int* col = ei + E;

    // High-water ~66 MB.
    ushort* xb    = (ushort*)d_ws;              // 12,800,000 us (x*dinv, bf16)
    ushort* aggxb = xb + 12800000;              // 12,800,000 us [N,128]
    ushort* xw2b  = aggxb;                      // IN-PLACE alias (fused gemm same-row)
    float*  dinv  = (float*)(aggxb + 12800000); // 102,400 f
    int*    deg   = (int*)(dinv + 102400);      // 102,400 i  (memset full padded span!)
    int*    off   = deg + 102400;               // 102,400 i
    int*    rank  = off + 102400;               // 1,600,000 i
    int*    rs    = rank + 1600000;             // 1,600,000 i
    int*    bsum  = rs + 1600000;               // 1,024 i
    ushort* wt1   = (ushort*)(bsum + 1024);     // 32,768 us each
    ushort* wt2   = wt1 + 32768;
    float*  outw  = (float*)d_out;

    const int nb = (M + 255) / 256;

    hipMemsetAsync(deg, 0, (size_t)102400 * sizeof(int), stream);

    deg_rank_kernel<<<(E + 255) / 256, 256, 0, stream>>>(col, deg, rank, E);
    dinv_kernel<<<(M + 255) / 256, 256, 0, stream>>>(deg, dinv, M);

    block_reduce_kernel<<<nb, 256, 0, stream>>>(deg, bsum, M);
    scan_bsum_kernel<<<1, 512, 0, stream>>>(bsum, nb);
    scan_offsets_kernel<<<nb, 256, 0, stream>>>(deg, bsum, off, M);

    fill_sorted_kernel<<<(E + 255) / 256, 256, 0, stream>>>(row, col, off, rank, rs, E);

    prep_weights<<<256, 256, 0, stream>>>(W1, W2, wt1, wt2);
    to_bf16_scaled_kernel<<<(M * 16 + 255) / 256, 256, 0, stream>>>(x, dinv, xb, M * 16);

    // layer 1 aggregate (self from table), bf16 out
    gather_sum_kernel<false, true><<<(M * 64 + 255) / 256, 256, 0, stream>>>(
        off, deg, rs, dinv, xb, nullptr, nullptr, aggxb, M);

    // fused MLP: 64 rows/block, plain-bf16 weights
    gemm_fused<<<(M + 63) / 64, 256, 0, stream>>>(aggxb, wt1, b1, wt2, dinv, xw2b, M);

    // layer 2 aggregate (self from table) + bias, fp32 out
    gather_sum_kernel<true, false><<<(M * 64 + 255) / 256, 256, 0, stream>>>(
        off, deg, rs, dinv, xw2b, b2, outw, nullptr, M);
}

// Round 16
// 301.825 us; speedup vs baseline: 1.2114x; 1.0062x over previous
//
#include <hip/hip_runtime.h>
#include <hip/hip_bf16.h>
#include <math.h>

typedef __attribute__((ext_vector_type(8))) short bf16x8;
typedef __attribute__((ext_vector_type(4))) float f32x4;

__device__ inline ushort f2bf(float f) {
    uint u = __float_as_uint(f);
    uint r = u + 0x7fffu + ((u >> 16) & 1u);
    return (ushort)(r >> 16);
}
__device__ inline float bf2f(ushort h) { return __uint_as_float(((uint)h) << 16); }

// gelu tanh-approx via sigmoid identity: 0.5x(1+tanh(z)) = x/(1+exp(-2z))
__device__ inline float gelu_fast(float x) {
    float z2 = 1.5957691216057308f * (x + 0.044715f * x * x * x);
    return x / (1.0f + __expf(-z2));
}

// ---------------- pass A: degree histogram + per-edge rank ----------------
// Counters padded to one per 64B L2 line: 1.6M atomics over 400KB was 256
// same-line RMWs per line (23 G/s); padding restores ~77 G/s class rates.

__global__ void deg_rank_kernel(const int* __restrict__ col, int* __restrict__ deg64,
                                int* __restrict__ rank, int E) {
    int e = blockIdx.x * blockDim.x + threadIdx.x;
    if (e < E) rank[e] = atomicAdd(&deg64[col[e] << 4], 1);
}

// reads padded counters, emits dinv + compact deg for the scan kernels
__global__ void dinv_kernel(const int* __restrict__ deg64, float* __restrict__ dinv,
                            int* __restrict__ deg, int M) {
    int i = blockIdx.x * blockDim.x + threadIdx.x;
    if (i < M) {
        int d = deg64[i << 4];
        deg[i] = d;
        dinv[i] = rsqrtf((float)d + 1.0f);   // +1 self loop
    }
}

// ---------------- hierarchical exclusive scan of deg -> off ----------------

__global__ void block_reduce_kernel(const int* __restrict__ deg, int* __restrict__ bsum, int M) {
    __shared__ int s[256];
    int i = blockIdx.x * 256 + threadIdx.x;
    s[threadIdx.x] = (i < M) ? deg[i] : 0;
    __syncthreads();
    for (int o = 128; o > 0; o >>= 1) {
        if (threadIdx.x < o) s[threadIdx.x] += s[threadIdx.x + o];
        __syncthreads();
    }
    if (threadIdx.x == 0) bsum[blockIdx.x] = s[0];
}

__global__ void scan_bsum_kernel(int* __restrict__ bsum, int nb) {
    __shared__ int s[512];
    int t = threadIdx.x;
    int orig = (t < nb) ? bsum[t] : 0;
    s[t] = orig;
    __syncthreads();
    for (int o = 1; o < 512; o <<= 1) {
        int v = 0;
        if (t >= o) v = s[t - o];
        __syncthreads();
        if (t >= o) s[t] += v;
        __syncthreads();
    }
    if (t < nb) bsum[t] = s[t] - orig;  // exclusive
}

__global__ void scan_offsets_kernel(const int* __restrict__ deg, const int* __restrict__ bsum,
                                    int* __restrict__ off, int M) {
    __shared__ int s[256];
    int i = blockIdx.x * 256 + threadIdx.x;
    int orig = (i < M) ? deg[i] : 0;
    s[threadIdx.x] = orig;
    __syncthreads();
    for (int o = 1; o < 256; o <<= 1) {
        int v = 0;
        if (threadIdx.x >= o) v = s[threadIdx.x - o];
        __syncthreads();
        if (threadIdx.x >= o) s[threadIdx.x] += v;
        __syncthreads();
    }
    if (i < M) off[i] = bsum[blockIdx.x] + s[threadIdx.x] - orig;  // exclusive
}

// ---------------- pass B: atomic-free CSR scatter ----------------

__global__ void fill_sorted_kernel(const int* __restrict__ row, const int* __restrict__ col,
                                   const int* __restrict__ off, const int* __restrict__ rank,
                                   int* __restrict__ rs, int E) {
    int e = blockIdx.x * blockDim.x + threadIdx.x;
    if (e < E) rs[off[col[e]] + rank[e]] = row[e];
}

// ---------------- weight prep: transpose + plain bf16 ----------------

__global__ void prep_weights(const float* __restrict__ W1, const float* __restrict__ W2,
                             ushort* __restrict__ wt1, ushort* __restrict__ wt2) {
    int idx = blockIdx.x * 256 + threadIdx.x;
    if (idx < 128 * 256) {
        int k = idx >> 8, n = idx & 255;
        wt1[n * 128 + k] = f2bf(W1[idx]);
    } else if (idx < 2 * 128 * 256) {
        int i2 = idx - 128 * 256;
        int k = i2 >> 7, n = i2 & 127;
        wt2[n * 256 + k] = f2bf(W2[i2]);
    }
}

// ---------------- x -> bf16 table scaled by dinv[node] (8 elems/thread) ----------------

__global__ void to_bf16_scaled_kernel(const float* __restrict__ in, const float* __restrict__ dinv,
                                      ushort* __restrict__ out, int n8) {
    int i = blockIdx.x * 256 + threadIdx.x;
    if (i >= n8) return;
    float s = dinv[i >> 4];
    float4 a = *(const float4*)(in + (size_t)i * 8);
    float4 b = *(const float4*)(in + (size_t)i * 8 + 4);
    ushort4 u0 = make_ushort4(f2bf(a.x * s), f2bf(a.y * s), f2bf(a.z * s), f2bf(a.w * s));
    ushort4 u1 = make_ushort4(f2bf(b.x * s), f2bf(b.y * s), f2bf(b.z * s), f2bf(b.w * s));
    *(ushort4*)(out + (size_t)i * 8) = u0;
    *(ushort4*)(out + (size_t)i * 8 + 4) = u1;
}

// ---------------- fused MLP: plain-bf16 weights, 64 rows/block ----------------
// Swapped-operand MFMA (C: node = lane&15, outcol = lk*4+reg).
// gemm1 reads A fragments directly from global (L2-warm); h via 32KB LDS.

__global__ __launch_bounds__(256, 2) void gemm_fused(const ushort* __restrict__ A,
                                                     const ushort* __restrict__ wt1,
                                                     const float* __restrict__ b1,
                                                     const ushort* __restrict__ wt2,
                                                     const float* __restrict__ dinv,
                                                     ushort* __restrict__ Cb, int M) {
    __shared__ ushort lh[64 * 256];   // h tile (row-XOR swizzled), 32KB

    const int t = threadIdx.x;
    const int R0 = blockIdx.x * 64;
    const int w = t >> 6, l = t & 63;
    const int lrow = l & 15;
    const int lk = l >> 4;

    // ---- hoist W1 fragments (wave w: outcols w*64..+63, K=128) ----
    bf16x8 w1[4][4];                  // 64 VGPR
    {
        const int c0 = w * 64;
        #pragma unroll
        for (int n = 0; n < 4; ++n) {
            int oc = c0 + n * 16 + lrow;
            #pragma unroll
            for (int ks = 0; ks < 4; ++ks) {
                int kb = ks * 32 + lk * 8;
                w1[n][ks] = *(const bf16x8*)&wt1[(size_t)oc * 128 + kb];
            }
        }
    }

    // ---- gemm1: direct-global A fragments + register W ----
    {
        const int c0 = w * 64;
        f32x4 acc[4][4] = {};          // [n outcol-tile][m node-tile]
        #pragma unroll
        for (int ks = 0; ks < 4; ++ks) {
            const int kb = ks * 32 + lk * 8;
            bf16x8 xf[4];
            #pragma unroll
            for (int m = 0; m < 4; ++m) {
                int gr = R0 + m * 16 + lrow;
                gr = gr < M ? gr : M - 1;          // clamp (tail block)
                xf[m] = *(const bf16x8*)(A + (size_t)gr * 128 + kb);
            }
            #pragma unroll
            for (int n = 0; n < 4; ++n)
                #pragma unroll
                for (int m = 0; m < 4; ++m)
                    acc[n][m] = __builtin_amdgcn_mfma_f32_16x16x32_bf16(w1[n][ks], xf[m], acc[n][m], 0, 0, 0);
        }
        // epilogue1: gelu(v+b1) -> packed 8B LDS stores
        #pragma unroll
        for (int n = 0; n < 4; ++n) {
            int ob = c0 + n * 16 + lk * 4;
            float4 bb = *(const float4*)(b1 + ob);
            #pragma unroll
            for (int m = 0; m < 4; ++m) {
                int nd = m * 16 + lrow;
                ushort4 pk;
                pk.x = f2bf(gelu_fast(acc[n][m][0] + bb.x));
                pk.y = f2bf(gelu_fast(acc[n][m][1] + bb.y));
                pk.z = f2bf(gelu_fast(acc[n][m][2] + bb.z));
                pk.w = f2bf(gelu_fast(acc[n][m][3] + bb.w));
                int byte = (nd * 256 + ob) * 2;
                byte ^= (nd & 7) << 4;
                *(ushort4*)((char*)lh + byte) = pk;
            }
        }
    }

    // ---- hoist W2 fragments (wave w: outcols2 w*32..+31, K=256) ----
    bf16x8 w2[2][8];                  // 64 VGPR (W1 regs dead now)
    {
        const int c0 = w * 32;
        #pragma unroll
        for (int n = 0; n < 2; ++n) {
            int oc = c0 + n * 16 + lrow;
            #pragma unroll
            for (int ks = 0; ks < 8; ++ks) {
                int kb = ks * 32 + lk * 8;
                w2[n][ks] = *(const bf16x8*)&wt2[(size_t)oc * 256 + kb];
            }
        }
    }
    __syncthreads();

    // ---- gemm2: LDS h + register W ----
    {
        const int c0 = w * 32;
        f32x4 acc2[2][4] = {};
        #pragma unroll
        for (int ks = 0; ks < 8; ++ks) {
            const int kb = ks * 32 + lk * 8;
            bf16x8 hf[4];
            #pragma unroll
            for (int m = 0; m < 4; ++m) {
                int nd = m * 16 + lrow;
                int byte = (nd * 256 + kb) * 2;
                byte ^= (nd & 7) << 4;
                hf[m] = *(const bf16x8*)((const char*)lh + byte);
            }
            #pragma unroll
            for (int n = 0; n < 2; ++n)
                #pragma unroll
                for (int m = 0; m < 4; ++m)
                    acc2[n][m] = __builtin_amdgcn_mfma_f32_16x16x32_bf16(w2[n][ks], hf[m], acc2[n][m], 0, 0, 0);
        }
        // epilogue2: dinv-scaled bf16, packed 8B global stores (in place)
        #pragma unroll
        for (int m = 0; m < 4; ++m) {
            int nd = m * 16 + lrow;
            int grow = R0 + nd;
            if (grow < M) {
                float sc = dinv[grow];
                #pragma unroll
                for (int n = 0; n < 2; ++n) {
                    int ob = c0 + n * 16 + lk * 4;
                    ushort4 pk;
                    pk.x = f2bf(acc2[n][m][0] * sc);
                    pk.y = f2bf(acc2[n][m][1] * sc);
                    pk.z = f2bf(acc2[n][m][2] * sc);
                    pk.w = f2bf(acc2[n][m][3] * sc);
                    *(ushort4*)(Cb + (size_t)grow * 128 + ob) = pk;
                }
            }
        }
    }
}

// ---------------- segment-sum gather, 8 edges in flight ----------------

template <bool BIAS, bool OUTBF>
__global__ __launch_bounds__(256) void gather_sum_kernel(const int* __restrict__ off,
                                                         const int* __restrict__ deg,
                                                         const int* __restrict__ rs,
                                                         const float* __restrict__ dinv,
                                                         const ushort* __restrict__ srcb,
                                                         const float* __restrict__ b,
                                                         float* __restrict__ dstf,
                                                         ushort* __restrict__ dstb, int M) {
    int wid = (blockIdx.x * 256 + threadIdx.x) >> 6;
    int lane = threadIdx.x & 63;
    int grp = lane >> 4;
    int l16 = lane & 15;
    if (wid >= M) return;
    int s0 = off[wid];
    int n = deg[wid];
    float acc[8] = {};
    float acc2[8] = {};

    if (grp == 0) {
        bf16x8 u = *(const bf16x8*)(srcb + (size_t)wid * 128 + l16 * 8);
        #pragma unroll
        for (int i = 0; i < 8; ++i) acc[i] += bf2f((ushort)u[i]);
    }

    int j = 0;
    for (; j + 8 <= n; j += 8) {
        int r0 = rs[s0 + j + grp];
        int r1 = rs[s0 + j + 4 + grp];
        bf16x8 u0 = *(const bf16x8*)(srcb + (size_t)r0 * 128 + l16 * 8);
        bf16x8 u1 = *(const bf16x8*)(srcb + (size_t)r1 * 128 + l16 * 8);
        #pragma unroll
        for (int i = 0; i < 8; ++i) {
            acc[i] += bf2f((ushort)u0[i]);
            acc2[i] += bf2f((ushort)u1[i]);
        }
    }
    if (j + 4 <= n) {
        int r = rs[s0 + j + grp];
        bf16x8 u = *(const bf16x8*)(srcb + (size_t)r * 128 + l16 * 8);
        #pragma unroll
        for (int i = 0; i < 8; ++i) acc[i] += bf2f((ushort)u[i]);
        j += 4;
    }
    if (j + grp < n) {
        int r = rs[s0 + j + grp];
        bf16x8 u = *(const bf16x8*)(srcb + (size_t)r * 128 + l16 * 8);
        #pragma unroll
        for (int i = 0; i < 8; ++i) acc2[i] += bf2f((ushort)u[i]);
    }

    #pragma unroll
    for (int i = 0; i < 8; ++i) {
        acc[i] += acc2[i];
        acc[i] += __shfl_xor(acc[i], 16);
        acc[i] += __shfl_xor(acc[i], 32);
    }

    if (grp == 0) {
        float sc = dinv[wid];
        #pragma unroll
        for (int i = 0; i < 8; ++i) acc[i] *= sc;
        if constexpr (BIAS) {
            float4 b0 = *(const float4*)(b + l16 * 8);
            float4 b1v = *(const float4*)(b + l16 * 8 + 4);
            acc[0] += b0.x; acc[1] += b0.y; acc[2] += b0.z; acc[3] += b0.w;
            acc[4] += b1v.x; acc[5] += b1v.y; acc[6] += b1v.z; acc[7] += b1v.w;
        }
        if constexpr (OUTBF) {
            bf16x8 o;
            #pragma unroll
            for (int i = 0; i < 8; ++i) o[i] = (short)f2bf(acc[i]);
            *(bf16x8*)(dstb + (size_t)wid * 128 + l16 * 8) = o;
        } else {
            float4 o0 = make_float4(acc[0], acc[1], acc[2], acc[3]);
            float4 o1 = make_float4(acc[4], acc[5], acc[6], acc[7]);
            *(float4*)(dstf + (size_t)wid * 128 + l16 * 8) = o0;
            *(float4*)(dstf + (size_t)wid * 128 + l16 * 8 + 4) = o1;
        }
    }
}

// ---------------- launch ----------------

extern "C" void kernel_launch(void* const* d_in, const int* in_sizes, int n_in,
                              void* d_out, int out_size, void* d_ws, size_t ws_size,
                              hipStream_t stream) {
    const float* x  = (const float*)d_in[0];
    const int*   ei = (const int*)d_in[1];
    const float* W1 = (const float*)d_in[2];
    const float* b1 = (const float*)d_in[3];
    const float* W2 = (const float*)d_in[4];
    const float* b2 = (const float*)d_in[5];

    const int M = in_sizes[0] / 128;      // 100000
    const int E = in_sizes[1] / 2;        // 1600000
    const int* row = ei;
    const int* col = ei + E;

    // High-water ~73 MB.
    ushort* xb    = (ushort*)d_ws;              // 12,800,000 us (x*dinv, bf16)
    ushort* aggxb = xb + 12800000;              // 12,800,000 us [N,128]
    ushort* xw2b  = aggxb;                      // IN-PLACE alias (fused gemm same-row)
    float*  dinv  = (float*)(aggxb + 12800000); // 102,400 f
    int*    deg64 = (int*)(dinv + 102400);      // 1,638,400 i (64B-padded counters)
    int*    deg   = deg64 + 1638400;            // 102,400 i (compact, for scans)
    int*    off   = deg + 102400;               // 102,400 i
    int*    rank  = off + 102400;               // 1,600,000 i
    int*    rs    = rank + 1600000;             // 1,600,000 i
    int*    bsum  = rs + 1600000;               // 1,024 i
    ushort* wt1   = (ushort*)(bsum + 1024);     // 32,768 us each
    ushort* wt2   = wt1 + 32768;
    float*  outw  = (float*)d_out;

    const int nb = (M + 255) / 256;

    hipMemsetAsync(deg64, 0, (size_t)1638400 * sizeof(int), stream);

    deg_rank_kernel<<<(E + 255) / 256, 256, 0, stream>>>(col, deg64, rank, E);
    dinv_kernel<<<(M + 255) / 256, 256, 0, stream>>>(deg64, dinv, deg, M);

    block_reduce_kernel<<<nb, 256, 0, stream>>>(deg, bsum, M);
    scan_bsum_kernel<<<1, 512, 0, stream>>>(bsum, nb);
    scan_offsets_kernel<<<nb, 256, 0, stream>>>(deg, bsum, off, M);

    fill_sorted_kernel<<<(E + 255) / 256, 256, 0, stream>>>(row, col, off, rank, rs, E);

    prep_weights<<<256, 256, 0, stream>>>(W1, W2, wt1, wt2);
    to_bf16_scaled_kernel<<<(M * 16 + 255) / 256, 256, 0, stream>>>(x, dinv, xb, M * 16);

    // layer 1 aggregate (self from table), bf16 out
    gather_sum_kernel<false, true><<<(M * 64 + 255) / 256, 256, 0, stream>>>(
        off, deg, rs, dinv, xb, nullptr, nullptr, aggxb, M);

    // fused MLP: 64 rows/block, plain-bf16 weights
    gemm_fused<<<(M + 63) / 64, 256, 0, stream>>>(aggxb, wt1, b1, wt2, dinv, xw2b, M);

    // layer 2 aggregate (self from table) + bias, fp32 out
    gather_sum_kernel<true, false><<<(M * 64 + 255) / 256, 256, 0, stream>>>(
        off, deg, rs, dinv, xw2b, b2, outw, nullptr, M);
}

// Round 17
// 278.187 us; speedup vs baseline: 1.3144x; 1.0850x over previous
//
#include <hip/hip_runtime.h>
#include <hip/hip_bf16.h>
#include <math.h>

typedef __attribute__((ext_vector_type(8))) short bf16x8;
typedef __attribute__((ext_vector_type(4))) float f32x4;

__device__ inline ushort f2bf(float f) {
    uint u = __float_as_uint(f);
    uint r = u + 0x7fffu + ((u >> 16) & 1u);
    return (ushort)(r >> 16);
}
__device__ inline float bf2f(ushort h) { return __uint_as_float(((uint)h) << 16); }

// gelu tanh-approx via sigmoid identity: 0.5x(1+tanh(z)) = x/(1+exp(-2z))
__device__ inline float gelu_fast(float x) {
    float z2 = 1.5957691216057308f * (x + 0.044715f * x * x * x);
    return x / (1.0f + __expf(-z2));
}

// ---------------- pass A: degree histogram + per-edge rank ----------------
// Counters padded to one per 64B L2 line (R15: unpadded was 256 RMWs/line).

__global__ void deg_rank_kernel(const int* __restrict__ col, int* __restrict__ deg64,
                                int* __restrict__ rank, int E) {
    int e = blockIdx.x * blockDim.x + threadIdx.x;
    if (e < E) rank[e] = atomicAdd(&deg64[col[e] << 4], 1);
}

// merged: dinv + compact deg + per-block sums (one pass over counters)
__global__ void dinv_reduce_kernel(const int* __restrict__ deg64, float* __restrict__ dinv,
                                   int* __restrict__ deg, int* __restrict__ bsum, int M) {
    __shared__ int s[256];
    int i = blockIdx.x * 256 + threadIdx.x;
    int d = 0;
    if (i < M) {
        d = deg64[i << 4];
        deg[i] = d;
        dinv[i] = rsqrtf((float)d + 1.0f);   // +1 self loop
    }
    s[threadIdx.x] = d;
    __syncthreads();
    for (int o = 128; o > 0; o >>= 1) {
        if (threadIdx.x < o) s[threadIdx.x] += s[threadIdx.x + o];
        __syncthreads();
    }
    if (threadIdx.x == 0) bsum[blockIdx.x] = s[0];
}

__global__ void scan_bsum_kernel(int* __restrict__ bsum, int nb) {
    __shared__ int s[512];
    int t = threadIdx.x;
    int orig = (t < nb) ? bsum[t] : 0;
    s[t] = orig;
    __syncthreads();
    for (int o = 1; o < 512; o <<= 1) {
        int v = 0;
        if (t >= o) v = s[t - o];
        __syncthreads();
        if (t >= o) s[t] += v;
        __syncthreads();
    }
    if (t < nb) bsum[t] = s[t] - orig;  // exclusive
}

__global__ void scan_offsets_kernel(const int* __restrict__ deg, const int* __restrict__ bsum,
                                    int* __restrict__ off, int M) {
    __shared__ int s[256];
    int i = blockIdx.x * 256 + threadIdx.x;
    int orig = (i < M) ? deg[i] : 0;
    s[threadIdx.x] = orig;
    __syncthreads();
    for (int o = 1; o < 256; o <<= 1) {
        int v = 0;
        if (threadIdx.x >= o) v = s[threadIdx.x - o];
        __syncthreads();
        if (threadIdx.x >= o) s[threadIdx.x] += v;
        __syncthreads();
    }
    if (i < M) off[i] = bsum[blockIdx.x] + s[threadIdx.x] - orig;  // exclusive
}

// ---------------- pass B: atomic-free CSR scatter ----------------

__global__ void fill_sorted_kernel(const int* __restrict__ row, const int* __restrict__ col,
                                   const int* __restrict__ off, const int* __restrict__ rank,
                                   int* __restrict__ rs, int E) {
    int e = blockIdx.x * blockDim.x + threadIdx.x;
    if (e < E) rs[off[col[e]] + rank[e]] = row[e];
}

// ---------------- merged prep: x->bf16*dinv table + fragment-packed weights ----------------
// p1/p2 hold the weights in EXACT per-wave fragment order: fragment (w,n,ks)
// for lane l is 8 contiguous shorts at ((group)*64 + l)*8 — a wave's load is
// one contiguous 1KB block (fully coalesced).

__global__ void prep_convert_kernel(const float* __restrict__ x, const float* __restrict__ dinv,
                                    const float* __restrict__ W1, const float* __restrict__ W2,
                                    ushort* __restrict__ xb, ushort* __restrict__ p1,
                                    ushort* __restrict__ p2, int n8) {
    int t = blockIdx.x * 256 + threadIdx.x;
    if (t < n8) {
        float s = dinv[t >> 4];
        float4 a = *(const float4*)(x + (size_t)t * 8);
        float4 b = *(const float4*)(x + (size_t)t * 8 + 4);
        ushort4 u0 = make_ushort4(f2bf(a.x * s), f2bf(a.y * s), f2bf(a.z * s), f2bf(a.w * s));
        ushort4 u1 = make_ushort4(f2bf(b.x * s), f2bf(b.y * s), f2bf(b.z * s), f2bf(b.w * s));
        *(ushort4*)(xb + (size_t)t * 8) = u0;
        *(ushort4*)(xb + (size_t)t * 8 + 4) = u1;
        return;
    }
    int u = t - n8;
    if (u < 4096) {                      // W1 pack: g = w*16 + n*4 + ks
        int g = u >> 6, l = u & 63;
        int w = g >> 4, n = (g >> 2) & 3, ks = g & 3;
        int oc = w * 64 + n * 16 + (l & 15);
        int kb = ks * 32 + (l >> 4) * 8;
        ushort tmp[8];
        #pragma unroll
        for (int j = 0; j < 8; ++j) tmp[j] = f2bf(W1[(size_t)(kb + j) * 256 + oc]);
        *(bf16x8*)(p1 + (size_t)u * 8) = *(bf16x8*)tmp;
    } else if (u < 8192) {               // W2 pack: g = w*16 + n*8 + ks
        int v = u - 4096;
        int g = v >> 6, l = v & 63;
        int w = g >> 4, n = (g >> 3) & 1, ks = g & 7;
        int oc = w * 32 + n * 16 + (l & 15);
        int kb = ks * 32 + (l >> 4) * 8;
        ushort tmp[8];
        #pragma unroll
        for (int j = 0; j < 8; ++j) tmp[j] = f2bf(W2[(size_t)(kb + j) * 128 + oc]);
        *(bf16x8*)(p2 + (size_t)v * 8) = *(bf16x8*)tmp;
    }
}

// ---------------- fused MLP v5: coalesced weight + LDS-staged A ----------------
// 64 rows/block, swapped-operand MFMA (C: node = lane&15, outcol = lk*4+reg).
// A staged to LDS with coalesced wave reads + row-XOR swizzle; weights from
// fragment-packed p1/p2 (one 1KB contiguous load per wave fragment).

__global__ __launch_bounds__(256, 2) void gemm_fused(const ushort* __restrict__ A,
                                                     const ushort* __restrict__ p1,
                                                     const float* __restrict__ b1,
                                                     const ushort* __restrict__ p2,
                                                     const float* __restrict__ dinv,
                                                     ushort* __restrict__ Cb, int M) {
    __shared__ ushort la[64 * 128];   // A tile, 16KB (row-XOR swizzled)
    __shared__ ushort lh[64 * 256];   // h tile, 32KB (row-XOR swizzled)

    const int t = threadIdx.x;
    const int R0 = blockIdx.x * 64;
    const int w = t >> 6, l = t & 63;
    const int lrow = l & 15;
    const int lk = l >> 4;

    // ---- stage A tile: coalesced reads (consecutive t -> consecutive 16B) ----
    #pragma unroll
    for (int base = 0; base < 1024; base += 256) {
        int idx = base + t;
        int r = idx >> 4;
        int c8 = idx & 15;
        int gr = R0 + r;
        gr = gr < M ? gr : M - 1;                    // clamp (tail block)
        bf16x8 v = *(const bf16x8*)(A + (size_t)gr * 128 + c8 * 8);
        int byte = idx * 16 ^ ((r & 7) << 4);        // swizzled write (conflict-free)
        *(bf16x8*)((char*)la + byte) = v;
    }

    // ---- hoist W1 fragments from packed p1 (overlaps A staging) ----
    bf16x8 w1[4][4];
    #pragma unroll
    for (int n = 0; n < 4; ++n)
        #pragma unroll
        for (int ks = 0; ks < 4; ++ks)
            w1[n][ks] = *(const bf16x8*)(p1 + (size_t)(((w * 4 + n) * 4 + ks) * 64 + l) * 8);
    __syncthreads();

    // ---- gemm1: LDS A + register W ----
    {
        const int c0 = w * 64;
        f32x4 acc[4][4] = {};          // [n outcol-tile][m node-tile]
        #pragma unroll
        for (int ks = 0; ks < 4; ++ks) {
            bf16x8 xf[4];
            #pragma unroll
            for (int m = 0; m < 4; ++m) {
                int nd = m * 16 + lrow;
                int byte = (nd * 256 + ks * 64 + lk * 16) ^ ((nd & 7) << 4);
                xf[m] = *(const bf16x8*)((const char*)la + byte);
            }
            #pragma unroll
            for (int n = 0; n < 4; ++n)
                #pragma unroll
                for (int m = 0; m < 4; ++m)
                    acc[n][m] = __builtin_amdgcn_mfma_f32_16x16x32_bf16(w1[n][ks], xf[m], acc[n][m], 0, 0, 0);
        }
        // epilogue1: gelu(v+b1) -> packed 8B LDS stores
        #pragma unroll
        for (int n = 0; n < 4; ++n) {
            int ob = c0 + n * 16 + lk * 4;
            float4 bb = *(const float4*)(b1 + ob);
            #pragma unroll
            for (int m = 0; m < 4; ++m) {
                int nd = m * 16 + lrow;
                ushort4 pk;
                pk.x = f2bf(gelu_fast(acc[n][m][0] + bb.x));
                pk.y = f2bf(gelu_fast(acc[n][m][1] + bb.y));
                pk.z = f2bf(gelu_fast(acc[n][m][2] + bb.z));
                pk.w = f2bf(gelu_fast(acc[n][m][3] + bb.w));
                int byte = (nd * 256 + ob) * 2;
                byte ^= (nd & 7) << 4;
                *(ushort4*)((char*)lh + byte) = pk;
            }
        }
    }

    // ---- hoist W2 fragments from packed p2 ----
    bf16x8 w2[2][8];
    #pragma unroll
    for (int n = 0; n < 2; ++n)
        #pragma unroll
        for (int ks = 0; ks < 8; ++ks)
            w2[n][ks] = *(const bf16x8*)(p2 + (size_t)(((w * 2 + n) * 8 + ks) * 64 + l) * 8);
    __syncthreads();

    // ---- gemm2: LDS h + register W ----
    {
        const int c0 = w * 32;
        f32x4 acc2[2][4] = {};
        #pragma unroll
        for (int ks = 0; ks < 8; ++ks) {
            const int kb = ks * 32 + lk * 8;
            bf16x8 hf[4];
            #pragma unroll
            for (int m = 0; m < 4; ++m) {
                int nd = m * 16 + lrow;
                int byte = (nd * 256 + kb) * 2;
                byte ^= (nd & 7) << 4;
                hf[m] = *(const bf16x8*)((const char*)lh + byte);
            }
            #pragma unroll
            for (int n = 0; n < 2; ++n)
                #pragma unroll
                for (int m = 0; m < 4; ++m)
                    acc2[n][m] = __builtin_amdgcn_mfma_f32_16x16x32_bf16(w2[n][ks], hf[m], acc2[n][m], 0, 0, 0);
        }
        // epilogue2: dinv-scaled bf16, packed 8B global stores (in place)
        #pragma unroll
        for (int m = 0; m < 4; ++m) {
            int nd = m * 16 + lrow;
            int grow = R0 + nd;
            if (grow < M) {
                float sc = dinv[grow];
                #pragma unroll
                for (int n = 0; n < 2; ++n) {
                    int ob = c0 + n * 16 + lk * 4;
                    ushort4 pk;
                    pk.x = f2bf(acc2[n][m][0] * sc);
                    pk.y = f2bf(acc2[n][m][1] * sc);
                    pk.z = f2bf(acc2[n][m][2] * sc);
                    pk.w = f2bf(acc2[n][m][3] * sc);
                    *(ushort4*)(Cb + (size_t)grow * 128 + ob) = pk;
                }
            }
        }
    }
}

// ---------------- segment-sum gather, 8 edges in flight ----------------

template <bool BIAS, bool OUTBF>
__global__ __launch_bounds__(256) void gather_sum_kernel(const int* __restrict__ off,
                                                         const int* __restrict__ deg,
                                                         const int* __restrict__ rs,
                                                         const float* __restrict__ dinv,
                                                         const ushort* __restrict__ srcb,
                                                         const float* __restrict__ b,
                                                         float* __restrict__ dstf,
                                                         ushort* __restrict__ dstb, int M) {
    int wid = (blockIdx.x * 256 + threadIdx.x) >> 6;
    int lane = threadIdx.x & 63;
    int grp = lane >> 4;
    int l16 = lane & 15;
    if (wid >= M) return;
    int s0 = off[wid];
    int n = deg[wid];
    float acc[8] = {};
    float acc2[8] = {};

    if (grp == 0) {
        bf16x8 u = *(const bf16x8*)(srcb + (size_t)wid * 128 + l16 * 8);
        #pragma unroll
        for (int i = 0; i < 8; ++i) acc[i] += bf2f((ushort)u[i]);
    }

    int j = 0;
    for (; j + 8 <= n; j += 8) {
        int r0 = rs[s0 + j + grp];
        int r1 = rs[s0 + j + 4 + grp];
        bf16x8 u0 = *(const bf16x8*)(srcb + (size_t)r0 * 128 + l16 * 8);
        bf16x8 u1 = *(const bf16x8*)(srcb + (size_t)r1 * 128 + l16 * 8);
        #pragma unroll
        for (int i = 0; i < 8; ++i) {
            acc[i] += bf2f((ushort)u0[i]);
            acc2[i] += bf2f((ushort)u1[i]);
        }
    }
    if (j + 4 <= n) {
        int r = rs[s0 + j + grp];
        bf16x8 u = *(const bf16x8*)(srcb + (size_t)r * 128 + l16 * 8);
        #pragma unroll
        for (int i = 0; i < 8; ++i) acc[i] += bf2f((ushort)u[i]);
        j += 4;
    }
    if (j + grp < n) {
        int r = rs[s0 + j + grp];
        bf16x8 u = *(const bf16x8*)(srcb + (size_t)r * 128 + l16 * 8);
        #pragma unroll
        for (int i = 0; i < 8; ++i) acc2[i] += bf2f((ushort)u[i]);
    }

    #pragma unroll
    for (int i = 0; i < 8; ++i) {
        acc[i] += acc2[i];
        acc[i] += __shfl_xor(acc[i], 16);
        acc[i] += __shfl_xor(acc[i], 32);
    }

    if (grp == 0) {
        float sc = dinv[wid];
        #pragma unroll
        for (int i = 0; i < 8; ++i) acc[i] *= sc;
        if constexpr (BIAS) {
            float4 b0 = *(const float4*)(b + l16 * 8);
            float4 b1v = *(const float4*)(b + l16 * 8 + 4);
            acc[0] += b0.x; acc[1] += b0.y; acc[2] += b0.z; acc[3] += b0.w;
            acc[4] += b1v.x; acc[5] += b1v.y; acc[6] += b1v.z; acc[7] += b1v.w;
        }
        if constexpr (OUTBF) {
            bf16x8 o;
            #pragma unroll
            for (int i = 0; i < 8; ++i) o[i] = (short)f2bf(acc[i]);
            *(bf16x8*)(dstb + (size_t)wid * 128 + l16 * 8) = o;
        } else {
            float4 o0 = make_float4(acc[0], acc[1], acc[2], acc[3]);
            float4 o1 = make_float4(acc[4], acc[5], acc[6], acc[7]);
            *(float4*)(dstf + (size_t)wid * 128 + l16 * 8) = o0;
            *(float4*)(dstf + (size_t)wid * 128 + l16 * 8 + 4) = o1;
        }
    }
}

// ---------------- launch ----------------

extern "C" void kernel_launch(void* const* d_in, const int* in_sizes, int n_in,
                              void* d_out, int out_size, void* d_ws, size_t ws_size,
                              hipStream_t stream) {
    const float* x  = (const float*)d_in[0];
    const int*   ei = (const int*)d_in[1];
    const float* W1 = (const float*)d_in[2];
    const float* b1 = (const float*)d_in[3];
    const float* W2 = (const float*)d_in[4];
    const float* b2 = (const float*)d_in[5];

    const int M = in_sizes[0] / 128;      // 100000
    const int E = in_sizes[1] / 2;        // 1600000
    const int* row = ei;
    const int* col = ei + E;

    // High-water ~73 MB.
    ushort* xb    = (ushort*)d_ws;              // 12,800,000 us (x*dinv, bf16)
    ushort* aggxb = xb + 12800000;              // 12,800,000 us [N,128]
    ushort* xw2b  = aggxb;                      // IN-PLACE alias (fused gemm same-row)
    float*  dinv  = (float*)(aggxb + 12800000); // 102,400 f
    int*    deg64 = (int*)(dinv + 102400);      // 1,638,400 i (64B-padded counters)
    int*    deg   = deg64 + 1638400;            // 102,400 i (compact, for scans)
    int*    off   = deg + 102400;               // 102,400 i
    int*    rank  = off + 102400;               // 1,600,000 i
    int*    rs    = rank + 1600000;             // 1,600,000 i
    int*    bsum  = rs + 1600000;               // 1,024 i
    ushort* p1    = (ushort*)(bsum + 1024);     // 32,768 us (W1 fragment-packed)
    ushort* p2    = p1 + 32768;                 // 32,768 us (W2 fragment-packed)
    float*  outw  = (float*)d_out;

    const int nb = (M + 255) / 256;

    hipMemsetAsync(deg64, 0, (size_t)1638400 * sizeof(int), stream);

    deg_rank_kernel<<<(E + 255) / 256, 256, 0, stream>>>(col, deg64, rank, E);
    dinv_reduce_kernel<<<nb, 256, 0, stream>>>(deg64, dinv, deg, bsum, M);
    scan_bsum_kernel<<<1, 512, 0, stream>>>(bsum, nb);
    scan_offsets_kernel<<<nb, 256, 0, stream>>>(deg, bsum, off, M);
    fill_sorted_kernel<<<(E + 255) / 256, 256, 0, stream>>>(row, col, off, rank, rs, E);

    prep_convert_kernel<<<(M * 16 + 8192 + 255) / 256, 256, 0, stream>>>(
        x, dinv, W1, W2, xb, p1, p2, M * 16);

    // layer 1 aggregate (self from table), bf16 out
    gather_sum_kernel<false, true><<<(M * 64 + 255) / 256, 256, 0, stream>>>(
        off, deg, rs, dinv, xb, nullptr, nullptr, aggxb, M);

    // fused MLP: 64 rows/block, packed weights + LDS-staged A
    gemm_fused<<<(M + 63) / 64, 256, 0, stream>>>(aggxb, p1, b1, p2, dinv, xw2b, M);

    // layer 2 aggregate (self from table) + bias, fp32 out
    gather_sum_kernel<true, false><<<(M * 64 + 255) / 256, 256, 0, stream>>>(
        off, deg, rs, dinv, xw2b, b2, outw, nullptr, M);
}